// Round 1
// baseline (1027.987 us; speedup 1.0000x reference)
//
#include <hip/hip_runtime.h>
#include <math.h>

static constexpr int Bb  = 16;
static constexpr int Nn  = 512;
static constexpr int Dd  = 512;
static constexpr int Hh  = 8;
static constexpr int HDd = 64;
static constexpr int UEe = 6;
static constexpr int DFFf= 2048;

// ---------------- block reduction helpers (256 threads, 4 waves) ----------------

__device__ __forceinline__ float2 block_sum2(float a, float b, float* sb) {
  #pragma unroll
  for (int o = 32; o; o >>= 1) { a += __shfl_down(a, o); b += __shfl_down(b, o); }
  const int lane = threadIdx.x & 63, wid = threadIdx.x >> 6;
  if (lane == 0) { sb[wid] = a; sb[4 + wid] = b; }
  __syncthreads();
  float ra = sb[0] + sb[1] + sb[2] + sb[3];
  float rb = sb[4] + sb[5] + sb[6] + sb[7];
  __syncthreads();
  return make_float2(ra, rb);
}

__device__ __forceinline__ float block_sum1(float a, float* sb) {
  #pragma unroll
  for (int o = 32; o; o >>= 1) a += __shfl_down(a, o);
  const int lane = threadIdx.x & 63, wid = threadIdx.x >> 6;
  if (lane == 0) sb[wid] = a;
  __syncthreads();
  float ra = sb[0] + sb[1] + sb[2] + sb[3];
  __syncthreads();
  return ra;
}

__device__ __forceinline__ float block_max1(float a, float* sb) {
  #pragma unroll
  for (int o = 32; o; o >>= 1) a = fmaxf(a, __shfl_down(a, o));
  const int lane = threadIdx.x & 63, wid = threadIdx.x >> 6;
  if (lane == 0) sb[wid] = a;
  __syncthreads();
  float ra = fmaxf(fmaxf(sb[0], sb[1]), fmaxf(sb[2], sb[3]));
  __syncthreads();
  return ra;
}

// ---------------- LayerNorm on x -> xn ----------------

__global__ __launch_bounds__(256) void ln1_kernel(
    const float* __restrict__ x, const float* __restrict__ w,
    const float* __restrict__ b, float* __restrict__ out) {
  __shared__ float sb[8];
  const size_t row = blockIdx.x;
  const int t = threadIdx.x;
  const float* xr = x + row * Dd;
  float2 xv = *(const float2*)(xr + 2 * t);
  float2 r = block_sum2(xv.x + xv.y, xv.x * xv.x + xv.y * xv.y, sb);
  const float mu = r.x * (1.f / Dd);
  const float var = r.y * (1.f / Dd) - mu * mu;
  const float rstd = rsqrtf(var + 1e-5f);
  float2 wv = *(const float2*)(w + 2 * t);
  float2 bv = *(const float2*)(b + 2 * t);
  float2 o;
  o.x = (xv.x - mu) * rstd * wv.x + bv.x;
  o.y = (xv.y - mu) * rstd * wv.y + bv.y;
  *(float2*)(out + row * Dd + 2 * t) = o;
}

// ---------------- LN2(attn_out)+residual -> h ; RMSNorm(h) -> z ----------------

__global__ __launch_bounds__(256) void hz_kernel(
    const float* __restrict__ ao, const float* __restrict__ xres,
    const float* __restrict__ w, const float* __restrict__ b,
    const float* __restrict__ rw,
    float* __restrict__ h, float* __restrict__ z) {
  __shared__ float sb[8];
  const size_t row = blockIdx.x;
  const int t = threadIdx.x;
  float2 av = *(const float2*)(ao + row * Dd + 2 * t);
  float2 r = block_sum2(av.x + av.y, av.x * av.x + av.y * av.y, sb);
  const float mu = r.x * (1.f / Dd);
  const float var = r.y * (1.f / Dd) - mu * mu;
  const float rstd = rsqrtf(var + 1e-5f);
  float2 wv = *(const float2*)(w + 2 * t);
  float2 bv = *(const float2*)(b + 2 * t);
  float2 xv = *(const float2*)(xres + row * Dd + 2 * t);
  float2 hv;
  hv.x = (av.x - mu) * rstd * wv.x + bv.x + xv.x;
  hv.y = (av.y - mu) * rstd * wv.y + bv.y + xv.y;
  *(float2*)(h + row * Dd + 2 * t) = hv;
  float ms = block_sum1(hv.x * hv.x + hv.y * hv.y, sb) * (1.f / Dd);
  const float rr = rsqrtf(ms + 1.1920929e-07f);
  float2 rwv = *(const float2*)(rw + 2 * t);
  float2 zv;
  zv.x = hv.x * rr * rwv.x;
  zv.y = hv.y * rr * rwv.y;
  *(float2*)(z + row * Dd + 2 * t) = zv;
}

// ---------------- row softmax (in place), rows of length 512 ----------------

__global__ __launch_bounds__(256) void softmax_kernel(float* __restrict__ p) {
  __shared__ float sb[8];
  const size_t row = blockIdx.x;
  const int t = threadIdx.x;
  float* pr = p + row * Nn;
  float2 v = *(const float2*)(pr + 2 * t);
  float M = block_max1(fmaxf(v.x, v.y), sb);
  float e0 = __expf(v.x - M), e1 = __expf(v.y - M);
  float S = block_sum1(e0 + e1, sb);
  const float r = 1.f / S;
  float2 o; o.x = e0 * r; o.y = e1 * r;
  *(float2*)(pr + 2 * t) = o;
}

// ---------------- generic tiled f32 GEMM ----------------
// C[M,Nc] = alpha * A[M,K] * op(B) + epilogue
// BMODE 0: B is [Nc,K] row-major (NT, weights).  BMODE 1: B is [K,Nc] row-major (NN).
// ADDR 0: linear batch strides sA/sB/sC * blockIdx.z
// ADDR 1 (scores): A,B use head addressing (b*N*D + h*HD), C = z*N*N
// ADDR 2 (ctx):    A = z*N*N, B,C head addressing
// EPI 0: none; 1: +bias[n]; 2: silu(+bias[n]); 3: +bias[n]+aux1[m,n];
// EPI 4: scores epilogue: alpha*acc + sum_c u_w[h,c]*u[b,c,i,j] + u_b[h]
template <int BM, int BN, int BK, int TM, int TN, int BMODE, int ADDR, int EPI>
__global__ __launch_bounds__((BM / TM) * (BN / TN)) void gemm_kernel(
    const float* __restrict__ A, const float* __restrict__ Bm,
    float* __restrict__ C, const float* __restrict__ bias,
    const float* __restrict__ aux1, const float* __restrict__ aux2,
    int M, int Nc, int K, int lda, int ldb, int ldc,
    long sA, long sB, long sC, float alpha) {
  static_assert(TN == 4, "epilogue assumes TN==4");
  constexpr int NTH = (BM / TM) * (BN / TN);
  __shared__ float As[BK][BM + 4];
  __shared__ float Bs[BK][BN + 4];
  const int tid = threadIdx.x;
  const int bx = blockIdx.x, by = blockIdx.y, bz = blockIdx.z;

  size_t offA, offB, offC;
  if constexpr (ADDR == 0) {
    offA = (size_t)bz * sA; offB = (size_t)bz * sB; offC = (size_t)bz * sC;
  } else {
    const int b = bz >> 3, hh = bz & 7;
    const size_t head = (size_t)b * (Nn * Dd) + (size_t)hh * HDd;
    if constexpr (ADDR == 1) {
      offA = head; offB = head; offC = (size_t)bz * ((size_t)Nn * Nn);
    } else {
      offA = (size_t)bz * ((size_t)Nn * Nn); offB = head; offC = head;
    }
  }
  const float* Ap = A + offA + (size_t)(by * BM) * lda;
  const float* Bp;
  if constexpr (BMODE == 0) Bp = Bm + offB + (size_t)(bx * BN) * ldb;
  else                      Bp = Bm + offB + bx * BN;

  const int txn = tid % (BN / TN);
  const int tym = tid / (BN / TN);
  float acc[TM][TN] = {};

  for (int k0 = 0; k0 < K; k0 += BK) {
    __syncthreads();
    {  // stage A tile (BM x BK), transpose into As[k][m]
      constexpr int TOT = BM * (BK / 4);
      #pragma unroll
      for (int it = 0; it < TOT / NTH; ++it) {
        const int id = tid + it * NTH;
        const int r = id / (BK / 4), c4 = id % (BK / 4);
        float4 va = *(const float4*)(Ap + (size_t)r * lda + k0 + c4 * 4);
        As[c4 * 4 + 0][r] = va.x; As[c4 * 4 + 1][r] = va.y;
        As[c4 * 4 + 2][r] = va.z; As[c4 * 4 + 3][r] = va.w;
      }
    }
    if constexpr (BMODE == 0) {  // B[Nc,K]: transpose into Bs[k][n]
      constexpr int TOT = BN * (BK / 4);
      #pragma unroll
      for (int it = 0; it < TOT / NTH; ++it) {
        const int id = tid + it * NTH;
        const int r = id / (BK / 4), c4 = id % (BK / 4);
        float4 vb = *(const float4*)(Bp + (size_t)r * ldb + k0 + c4 * 4);
        Bs[c4 * 4 + 0][r] = vb.x; Bs[c4 * 4 + 1][r] = vb.y;
        Bs[c4 * 4 + 2][r] = vb.z; Bs[c4 * 4 + 3][r] = vb.w;
      }
    } else {  // B[K,Nc]: direct vector store
      constexpr int TOT = BK * (BN / 4);
      #pragma unroll
      for (int it = 0; it < (TOT + NTH - 1) / NTH; ++it) {
        const int id = tid + it * NTH;
        if (TOT % NTH == 0 || id < TOT) {
          const int r = id / (BN / 4), c4 = id % (BN / 4);
          float4 vb = *(const float4*)(Bp + (size_t)(k0 + r) * ldb + c4 * 4);
          *(float4*)&Bs[r][c4 * 4] = vb;
        }
      }
    }
    __syncthreads();
    #pragma unroll
    for (int kk = 0; kk < BK; ++kk) {
      float af[TM], bf[TN];
      #pragma unroll
      for (int i = 0; i < TM; ++i) af[i] = As[kk][tym * TM + i];
      #pragma unroll
      for (int j = 0; j < TN; ++j) bf[j] = Bs[kk][txn * TN + j];
      #pragma unroll
      for (int i = 0; i < TM; ++i)
        #pragma unroll
        for (int j = 0; j < TN; ++j)
          acc[i][j] = fmaf(af[i], bf[j], acc[i][j]);
    }
  }

  // ---- epilogue ----
  float* Cp = C + offC;
  const int gn0 = bx * BN + txn * TN;
  const int gm0 = by * BM + tym * TM;

  if constexpr (EPI == 4) {
    const int b = bz >> 3, hh = bz & 7;
    const float* up = aux1 + (size_t)b * UEe * Nn * Nn + gn0;
    float uw[UEe];
    #pragma unroll
    for (int c = 0; c < UEe; ++c) uw[c] = aux2[hh * UEe + c];
    const float ubh = bias[hh];
    #pragma unroll
    for (int i = 0; i < TM; ++i) {
      const size_t ri = (size_t)(gm0 + i) * Nn;
      float4 r = make_float4(acc[i][0] * alpha + ubh, acc[i][1] * alpha + ubh,
                             acc[i][2] * alpha + ubh, acc[i][3] * alpha + ubh);
      #pragma unroll
      for (int c = 0; c < UEe; ++c) {
        float4 uv = *(const float4*)(up + (size_t)c * Nn * Nn + ri);
        r.x = fmaf(uw[c], uv.x, r.x); r.y = fmaf(uw[c], uv.y, r.y);
        r.z = fmaf(uw[c], uv.z, r.z); r.w = fmaf(uw[c], uv.w, r.w);
      }
      *(float4*)(Cp + (size_t)(gm0 + i) * ldc + gn0) = r;
    }
  } else {
    #pragma unroll
    for (int i = 0; i < TM; ++i) {
      float4 r = make_float4(acc[i][0], acc[i][1], acc[i][2], acc[i][3]);
      if constexpr (EPI >= 1) {
        r.x += bias[gn0 + 0]; r.y += bias[gn0 + 1];
        r.z += bias[gn0 + 2]; r.w += bias[gn0 + 3];
      }
      if constexpr (EPI == 2) {
        r.x *= 1.f / (1.f + __expf(-r.x)); r.y *= 1.f / (1.f + __expf(-r.y));
        r.z *= 1.f / (1.f + __expf(-r.z)); r.w *= 1.f / (1.f + __expf(-r.w));
      }
      if constexpr (EPI == 3) {
        float4 hv = *(const float4*)(aux1 + (size_t)(gm0 + i) * ldc + gn0);
        r.x += hv.x; r.y += hv.y; r.z += hv.z; r.w += hv.w;
      }
      *(float4*)(Cp + (size_t)(gm0 + i) * ldc + gn0) = r;
    }
  }
}

// ---------------- host launch ----------------

extern "C" void kernel_launch(void* const* d_in, const int* in_sizes, int n_in,
                              void* d_out, int out_size, void* d_ws, size_t ws_size,
                              hipStream_t stream) {
  const float* x     = (const float*)d_in[0];
  const float* u     = (const float*)d_in[1];
  const float* ln1_w = (const float*)d_in[2];
  const float* ln1_b = (const float*)d_in[3];
  const float* ln2_w = (const float*)d_in[4];
  const float* ln2_b = (const float*)d_in[5];
  const float* wq    = (const float*)d_in[6];
  const float* wk    = (const float*)d_in[7];
  const float* wv    = (const float*)d_in[8];
  const float* wo    = (const float*)d_in[9];
  const float* bo    = (const float*)d_in[10];
  const float* u_w   = (const float*)d_in[11];
  const float* u_b   = (const float*)d_in[12];
  const float* rms_w = (const float*)d_in[13];
  const float* w1    = (const float*)d_in[14];
  const float* b1    = (const float*)d_in[15];
  const float* w2    = (const float*)d_in[16];
  const float* b2    = (const float*)d_in[17];

  float* out   = (float*)d_out;
  float* attnW = out + (size_t)Bb * Nn * Dd;  // second output: [B,H,N,N]

  const size_t RSZ = (size_t)Bb * Nn * Dd;  // 4194304 floats
  float* ws   = (float*)d_ws;
  float* xn   = ws + 0 * RSZ;  // R0: xn -> ctx -> z
  float* qb   = ws + 1 * RSZ;  // R1: q -> attn_out
  float* kb   = ws + 2 * RSZ;  // R2: k -> h
  float* vb   = ws + 3 * RSZ;  // R3: v -> (zf starts here)
  float* ctx  = xn;
  float* aout = qb;
  float* hbuf = kb;
  float* zbuf = xn;
  float* zf   = vb;

  const int MR = Bb * Nn;  // 8192 rows

  // 1. LayerNorm1
  ln1_kernel<<<MR, 256, 0, stream>>>(x, ln1_w, ln1_b, xn);

  // 2. Q,K,V projections: [8192,512] = xn @ W^T
  dim3 gProj(Dd / 64, MR / 128, 1);
  gemm_kernel<128,64,16,8,4,0,0,0><<<gProj,256,0,stream>>>(
      xn, wq, qb, nullptr, nullptr, nullptr, MR, Dd, Dd, Dd, Dd, Dd, 0,0,0, 1.f);
  gemm_kernel<128,64,16,8,4,0,0,0><<<gProj,256,0,stream>>>(
      xn, wk, kb, nullptr, nullptr, nullptr, MR, Dd, Dd, Dd, Dd, Dd, 0,0,0, 1.f);
  gemm_kernel<128,64,16,8,4,0,0,0><<<gProj,256,0,stream>>>(
      xn, wv, vb, nullptr, nullptr, nullptr, MR, Dd, Dd, Dd, Dd, Dd, 0,0,0, 1.f);

  // 3. scores = 8 * q k^T + u-bias  -> attnW (raw scores)
  dim3 gSc(Nn / 64, Nn / 128, Bb * Hh);
  gemm_kernel<128,64,16,8,4,0,1,4><<<gSc,256,0,stream>>>(
      qb, kb, attnW, u_b, u, u_w, Nn, Nn, HDd, Dd, Dd, Nn, 0,0,0, 8.f);

  // 4. softmax rows (in place in d_out attn region)
  softmax_kernel<<<Bb * Hh * Nn, 256, 0, stream>>>(attnW);

  // 5. ctx = attn @ v  (NN GEMM, per-head)
  dim3 gCtx(1, Nn / 64, Bb * Hh);
  gemm_kernel<64,64,16,4,4,1,2,0><<<gCtx,256,0,stream>>>(
      attnW, vb, ctx, nullptr, nullptr, nullptr, Nn, HDd, Nn, Nn, Dd, Dd, 0,0,0, 1.f);

  // 6. attn_out = ctx @ wo^T + bo
  gemm_kernel<128,64,16,8,4,0,0,1><<<gProj,256,0,stream>>>(
      ctx, wo, aout, bo, nullptr, nullptr, MR, Dd, Dd, Dd, Dd, Dd, 0,0,0, 1.f);

  // 7. h = LN2(attn_out) + x ; z = RMSNorm(h)
  hz_kernel<<<MR, 256, 0, stream>>>(aout, x, ln2_w, ln2_b, rms_w, hbuf, zbuf);

  // 8/9. FFN, chunked over rows so zf fits in remaining workspace
  const size_t baseFloats = 3 * RSZ;  // zf region starts after R0..R2 live bufs (vb reused)
  size_t avail = ws_size / 4 > baseFloats ? ws_size / 4 - baseFloats : 0;
  int rows = MR;
  while (rows > 128 && (size_t)rows * DFFf > avail) rows >>= 1;
  for (int m0 = 0; m0 < MR; m0 += rows) {
    dim3 gF1(DFFf / 64, rows / 128, 1);
    gemm_kernel<128,64,16,8,4,0,0,2><<<gF1,256,0,stream>>>(
        zbuf + (size_t)m0 * Dd, w1, zf, b1, nullptr, nullptr,
        rows, DFFf, Dd, Dd, Dd, DFFf, 0,0,0, 1.f);
    dim3 gF2(Dd / 64, rows / 128, 1);
    gemm_kernel<128,64,16,8,4,0,0,3><<<gF2,256,0,stream>>>(
        zf, w2, out + (size_t)m0 * Dd, b2, hbuf + (size_t)m0 * Dd, nullptr,
        rows, Dd, DFFf, DFFf, DFFf, Dd, 0,0,0, 1.f);
  }
}

// Round 3
// 620.910 us; speedup vs baseline: 1.6556x; 1.6556x over previous
//
#include <hip/hip_runtime.h>
#include <math.h>

static constexpr int Bb  = 16;
static constexpr int Nn  = 512;
static constexpr int Dd  = 512;
static constexpr int Hh  = 8;
static constexpr int HDd = 64;
static constexpr int UEe = 6;
static constexpr int DFFf= 2048;

typedef __attribute__((ext_vector_type(8))) short short8v;
typedef __attribute__((ext_vector_type(4))) float f32x4;

__device__ __forceinline__ short f2bf(float f) {
  unsigned u = __float_as_uint(f);
  unsigned r = (u + 0x7fffu + ((u >> 16) & 1u)) >> 16;
  return (short)r;
}

// ---------------- block reduction helpers (256 threads, 4 waves) ----------------

__device__ __forceinline__ float2 block_sum2(float a, float b, float* sb) {
  #pragma unroll
  for (int o = 32; o; o >>= 1) { a += __shfl_down(a, o); b += __shfl_down(b, o); }
  const int lane = threadIdx.x & 63, wid = threadIdx.x >> 6;
  if (lane == 0) { sb[wid] = a; sb[4 + wid] = b; }
  __syncthreads();
  float ra = sb[0] + sb[1] + sb[2] + sb[3];
  float rb = sb[4] + sb[5] + sb[6] + sb[7];
  __syncthreads();
  return make_float2(ra, rb);
}

__device__ __forceinline__ float block_sum1(float a, float* sb) {
  #pragma unroll
  for (int o = 32; o; o >>= 1) a += __shfl_down(a, o);
  const int lane = threadIdx.x & 63, wid = threadIdx.x >> 6;
  if (lane == 0) sb[wid] = a;
  __syncthreads();
  float ra = sb[0] + sb[1] + sb[2] + sb[3];
  __syncthreads();
  return ra;
}

__device__ __forceinline__ float block_max1(float a, float* sb) {
  #pragma unroll
  for (int o = 32; o; o >>= 1) a = fmaxf(a, __shfl_down(a, o));
  const int lane = threadIdx.x & 63, wid = threadIdx.x >> 6;
  if (lane == 0) sb[wid] = a;
  __syncthreads();
  float ra = fmaxf(fmaxf(sb[0], sb[1]), fmaxf(sb[2], sb[3]));
  __syncthreads();
  return ra;
}

// ---------------- LayerNorm on x -> xn ----------------

__global__ __launch_bounds__(256) void ln1_kernel(
    const float* __restrict__ x, const float* __restrict__ w,
    const float* __restrict__ b, float* __restrict__ out) {
  __shared__ float sb[8];
  const size_t row = blockIdx.x;
  const int t = threadIdx.x;
  const float* xr = x + row * Dd;
  float2 xv = *(const float2*)(xr + 2 * t);
  float2 r = block_sum2(xv.x + xv.y, xv.x * xv.x + xv.y * xv.y, sb);
  const float mu = r.x * (1.f / Dd);
  const float var = r.y * (1.f / Dd) - mu * mu;
  const float rstd = rsqrtf(var + 1e-5f);
  float2 wv = *(const float2*)(w + 2 * t);
  float2 bv = *(const float2*)(b + 2 * t);
  float2 o;
  o.x = (xv.x - mu) * rstd * wv.x + bv.x;
  o.y = (xv.y - mu) * rstd * wv.y + bv.y;
  *(float2*)(out + row * Dd + 2 * t) = o;
}

// ------- LN2(attn_out)+residual -> h (f32) ; RMSNorm(h) -> zbf (bf16) -------

__global__ __launch_bounds__(256) void hz_kernel(
    const float* __restrict__ ao, const float* __restrict__ xres,
    const float* __restrict__ w, const float* __restrict__ b,
    const float* __restrict__ rw,
    float* __restrict__ h, short* __restrict__ zbf) {
  __shared__ float sb[8];
  const size_t row = blockIdx.x;
  const int t = threadIdx.x;
  float2 av = *(const float2*)(ao + row * Dd + 2 * t);
  float2 r = block_sum2(av.x + av.y, av.x * av.x + av.y * av.y, sb);
  const float mu = r.x * (1.f / Dd);
  const float var = r.y * (1.f / Dd) - mu * mu;
  const float rstd = rsqrtf(var + 1e-5f);
  float2 wv = *(const float2*)(w + 2 * t);
  float2 bv = *(const float2*)(b + 2 * t);
  float2 xv = *(const float2*)(xres + row * Dd + 2 * t);
  float2 hv;
  hv.x = (av.x - mu) * rstd * wv.x + bv.x + xv.x;
  hv.y = (av.y - mu) * rstd * wv.y + bv.y + xv.y;
  *(float2*)(h + row * Dd + 2 * t) = hv;
  float ms = block_sum1(hv.x * hv.x + hv.y * hv.y, sb) * (1.f / Dd);
  const float rr = rsqrtf(ms + 1.1920929e-07f);
  float2 rwv = *(const float2*)(rw + 2 * t);
  short2 zv;
  zv.x = f2bf(hv.x * rr * rwv.x);
  zv.y = f2bf(hv.y * rr * rwv.y);
  *(short2*)(zbf + row * Dd + 2 * t) = zv;
}

// ---------------- row softmax (in place), rows of length 512 ----------------

__global__ __launch_bounds__(256) void softmax_kernel(float* __restrict__ p) {
  __shared__ float sb[8];
  const size_t row = blockIdx.x;
  const int t = threadIdx.x;
  float* pr = p + row * Nn;
  float2 v = *(const float2*)(pr + 2 * t);
  float M = block_max1(fmaxf(v.x, v.y), sb);
  float e0 = __expf(v.x - M), e1 = __expf(v.y - M);
  float S = block_sum1(e0 + e1, sb);
  const float r = 1.f / S;
  float2 o; o.x = e0 * r; o.y = e1 * r;
  *(float2*)(pr + 2 * t) = o;
}

// ---------------- f32 -> bf16 convert ----------------

__global__ __launch_bounds__(256) void cvt_kernel(
    const float* __restrict__ in, short* __restrict__ out, int n4) {
  int i = blockIdx.x * 256 + threadIdx.x;
  if (i < n4) {
    float4 v = ((const float4*)in)[i];
    short4 o;
    o.x = f2bf(v.x); o.y = f2bf(v.y); o.z = f2bf(v.z); o.w = f2bf(v.w);
    ((short4*)out)[i] = o;
  }
}

// ---------------- dedicated ctx kernel: ctx = attn @ v (per head) ----------------
// grid (Nn/128, B*H); 256 threads; 128x64 tile, BK=32, TM=8, TN=4.

__global__ __launch_bounds__(256) void ctx_kernel(
    const float* __restrict__ attn, const float* __restrict__ v,
    float* __restrict__ ctx) {
  __shared__ float As[128][36];  // XOR-swizzled k-quad columns
  __shared__ float Bs[32][68];
  const int z = blockIdx.y, b = z >> 3, hh = z & 7;
  const float* Ap = attn + (size_t)z * Nn * Nn + (size_t)blockIdx.x * 128 * Nn;
  const float* Bp = v + (size_t)b * Nn * Dd + hh * HDd;
  float* Cp = ctx + (size_t)b * Nn * Dd + hh * HDd + (size_t)blockIdx.x * 128 * Dd;
  const int tid = threadIdx.x;
  const int txn = tid & 15, tym = tid >> 4;
  float acc[8][4] = {};
  for (int k0 = 0; k0 < Nn; k0 += 32) {
    __syncthreads();
    #pragma unroll
    for (int it = 0; it < 4; ++it) {  // A: 128x32 f32
      int id = tid + it * 256;
      int r = id >> 3, c4 = id & 7;
      float4 va = *(const float4*)(Ap + (size_t)r * Nn + k0 + c4 * 4);
      *(float4*)&As[r][(c4 ^ ((r >> 3) & 3)) << 2] = va;
    }
    #pragma unroll
    for (int it = 0; it < 2; ++it) {  // B: 32x64 f32
      int id = tid + it * 256;
      int r = id >> 4, c4 = id & 15;
      *(float4*)&Bs[r][c4 * 4] = *(const float4*)(Bp + (size_t)(k0 + r) * Dd + c4 * 4);
    }
    __syncthreads();
    #pragma unroll
    for (int kk4 = 0; kk4 < 8; ++kk4) {
      float4 a4[8];
      #pragma unroll
      for (int i = 0; i < 8; ++i)
        a4[i] = *(const float4*)&As[tym * 8 + i][(kk4 ^ (tym & 3)) << 2];
      #pragma unroll
      for (int q = 0; q < 4; ++q) {
        float4 b4 = *(const float4*)&Bs[kk4 * 4 + q][txn * 4];
        #pragma unroll
        for (int i = 0; i < 8; ++i) {
          float a = (q == 0) ? a4[i].x : (q == 1) ? a4[i].y : (q == 2) ? a4[i].z : a4[i].w;
          acc[i][0] = fmaf(a, b4.x, acc[i][0]);
          acc[i][1] = fmaf(a, b4.y, acc[i][1]);
          acc[i][2] = fmaf(a, b4.z, acc[i][2]);
          acc[i][3] = fmaf(a, b4.w, acc[i][3]);
        }
      }
    }
  }
  #pragma unroll
  for (int i = 0; i < 8; ++i)
    *(float4*)(Cp + (size_t)(tym * 8 + i) * Dd + txn * 4) =
        make_float4(acc[i][0], acc[i][1], acc[i][2], acc[i][3]);
}

// ---------------- bf16 MFMA NT GEMM: C[M,Nc] = A[M,K] @ W[Nc,K]^T ----------------
// EPI 0: silu(acc + bias) -> bf16 out.  EPI 1: acc + bias + res -> f32 out.
// 256 threads = 4 waves in 2x2; per-wave tile (BM/2)x(BN/2); 16x16x32 bf16 MFMA.

template <int BM, int BN, int EPI>
__global__ __launch_bounds__(256) void mfma_nt_kernel(
    const short* __restrict__ Ag, const short* __restrict__ Wg,
    void* __restrict__ Cv, const float* __restrict__ bias,
    const float* __restrict__ res, int Nc, int K) {
  constexpr int MREP = BM / 32, NREP = BN / 32;
  __shared__ short As[BM][72];
  __shared__ short Bs[BN][72];
  const int tid = threadIdx.x;
  const int wave = tid >> 6, lane = tid & 63;
  const int wr = wave >> 1, wc = wave & 1;
  const int lrow = lane & 15, kblk = lane >> 4;
  const size_t bm = (size_t)blockIdx.y * BM, bn = (size_t)blockIdx.x * BN;
  f32x4 acc[MREP][NREP] = {};
  for (int k0 = 0; k0 < K; k0 += 32) {
    __syncthreads();
    #pragma unroll
    for (int it = 0; it < BM / 64; ++it) {
      int id = tid + it * 256;
      int r = id >> 2, kq = id & 3;
      *(short8v*)&As[r][kq * 8] = *(const short8v*)(Ag + (bm + r) * K + k0 + kq * 8);
    }
    #pragma unroll
    for (int it = 0; it < BN / 64; ++it) {
      int id = tid + it * 256;
      int r = id >> 2, kq = id & 3;
      *(short8v*)&Bs[r][kq * 8] = *(const short8v*)(Wg + (bn + r) * K + k0 + kq * 8);
    }
    __syncthreads();
    short8v af[MREP], bf[NREP];
    #pragma unroll
    for (int i = 0; i < MREP; ++i)
      af[i] = *(const short8v*)&As[wr * (BM / 2) + i * 16 + lrow][kblk * 8];
    #pragma unroll
    for (int j = 0; j < NREP; ++j)
      bf[j] = *(const short8v*)&Bs[wc * (BN / 2) + j * 16 + lrow][kblk * 8];
    #pragma unroll
    for (int i = 0; i < MREP; ++i)
      #pragma unroll
      for (int j = 0; j < NREP; ++j)
        acc[i][j] = __builtin_amdgcn_mfma_f32_16x16x32_bf16(af[i], bf[j], acc[i][j], 0, 0, 0);
  }
  #pragma unroll
  for (int i = 0; i < MREP; ++i) {
    #pragma unroll
    for (int j = 0; j < NREP; ++j) {
      const size_t gcol = bn + wc * (BN / 2) + j * 16 + lrow;
      const float bb = bias[gcol];
      #pragma unroll
      for (int reg = 0; reg < 4; ++reg) {
        const size_t grow = bm + wr * (BM / 2) + i * 16 + kblk * 4 + reg;
        float vv = acc[i][j][reg] + bb;
        if constexpr (EPI == 0) {
          vv = vv / (1.f + __expf(-vv));
          ((short*)Cv)[grow * Nc + gcol] = f2bf(vv);
        } else {
          ((float*)Cv)[grow * Nc + gcol] = vv + res[grow * Nc + gcol];
        }
      }
    }
  }
}

// ---------------- generic tiled f32 GEMM (proj / scores / outproj) ----------------
template <int BM, int BN, int BK, int TM, int TN, int ADDR, int EPI>
__global__ __launch_bounds__((BM / TM) * (BN / TN)) void gemm_kernel(
    const float* __restrict__ A, const float* __restrict__ Bm,
    float* __restrict__ C, const float* __restrict__ bias,
    const float* __restrict__ aux1, const float* __restrict__ aux2,
    int M, int Nc, int K, int lda, int ldb, int ldc, float alpha) {
  static_assert(TN == 4, "epilogue assumes TN==4");
  constexpr int NTH = (BM / TM) * (BN / TN);
  __shared__ float As[BK][BM + 4];
  __shared__ float Bs[BK][BN + 4];
  const int tid = threadIdx.x;
  const int bx = blockIdx.x, by = blockIdx.y, bz = blockIdx.z;

  size_t offA, offB, offC;
  if constexpr (ADDR == 0) {
    offA = 0; offB = 0; offC = 0;
  } else {  // scores addressing
    const int b = bz >> 3, hh = bz & 7;
    const size_t head = (size_t)b * (Nn * Dd) + (size_t)hh * HDd;
    offA = head; offB = head; offC = (size_t)bz * ((size_t)Nn * Nn);
  }
  const float* Ap = A + offA + (size_t)(by * BM) * lda;
  const float* Bp = Bm + offB + (size_t)(bx * BN) * ldb;

  const int txn = tid % (BN / TN);
  const int tym = tid / (BN / TN);
  float acc[TM][TN] = {};

  for (int k0 = 0; k0 < K; k0 += BK) {
    __syncthreads();
    {  // stage A tile (BM x BK), transpose into As[k][m]
      constexpr int TOT = BM * (BK / 4);
      #pragma unroll
      for (int it = 0; it < TOT / NTH; ++it) {
        const int id = tid + it * NTH;
        const int r = id / (BK / 4), c4 = id % (BK / 4);
        float4 va = *(const float4*)(Ap + (size_t)r * lda + k0 + c4 * 4);
        As[c4 * 4 + 0][r] = va.x; As[c4 * 4 + 1][r] = va.y;
        As[c4 * 4 + 2][r] = va.z; As[c4 * 4 + 3][r] = va.w;
      }
    }
    {  // stage B tile [Nc,K] transposed into Bs[k][n]
      constexpr int TOT = BN * (BK / 4);
      #pragma unroll
      for (int it = 0; it < TOT / NTH; ++it) {
        const int id = tid + it * NTH;
        const int r = id / (BK / 4), c4 = id % (BK / 4);
        float4 vb = *(const float4*)(Bp + (size_t)r * ldb + k0 + c4 * 4);
        Bs[c4 * 4 + 0][r] = vb.x; Bs[c4 * 4 + 1][r] = vb.y;
        Bs[c4 * 4 + 2][r] = vb.z; Bs[c4 * 4 + 3][r] = vb.w;
      }
    }
    __syncthreads();
    #pragma unroll
    for (int kk = 0; kk < BK; ++kk) {
      float af[TM], bf[TN];
      #pragma unroll
      for (int i = 0; i < TM; ++i) af[i] = As[kk][tym * TM + i];
      #pragma unroll
      for (int j = 0; j < TN; ++j) bf[j] = Bs[kk][txn * TN + j];
      #pragma unroll
      for (int i = 0; i < TM; ++i)
        #pragma unroll
        for (int j = 0; j < TN; ++j)
          acc[i][j] = fmaf(af[i], bf[j], acc[i][j]);
    }
  }

  float* Cp = C + offC;
  const int gn0 = bx * BN + txn * TN;
  const int gm0 = by * BM + tym * TM;

  if constexpr (EPI == 4) {  // scores epilogue
    const int b = bz >> 3, hh = bz & 7;
    const float* up = aux1 + (size_t)b * UEe * Nn * Nn + gn0;
    float uw[UEe];
    #pragma unroll
    for (int c = 0; c < UEe; ++c) uw[c] = aux2[hh * UEe + c];
    const float ubh = bias[hh];
    #pragma unroll
    for (int i = 0; i < TM; ++i) {
      const size_t ri = (size_t)(gm0 + i) * Nn;
      float4 r = make_float4(acc[i][0] * alpha + ubh, acc[i][1] * alpha + ubh,
                             acc[i][2] * alpha + ubh, acc[i][3] * alpha + ubh);
      #pragma unroll
      for (int c = 0; c < UEe; ++c) {
        float4 uv = *(const float4*)(up + (size_t)c * Nn * Nn + ri);
        r.x = fmaf(uw[c], uv.x, r.x); r.y = fmaf(uw[c], uv.y, r.y);
        r.z = fmaf(uw[c], uv.z, r.z); r.w = fmaf(uw[c], uv.w, r.w);
      }
      *(float4*)(Cp + (size_t)(gm0 + i) * ldc + gn0) = r;
    }
  } else {
    #pragma unroll
    for (int i = 0; i < TM; ++i) {
      float4 r = make_float4(acc[i][0], acc[i][1], acc[i][2], acc[i][3]);
      if constexpr (EPI >= 1) {
        r.x += bias[gn0 + 0]; r.y += bias[gn0 + 1];
        r.z += bias[gn0 + 2]; r.w += bias[gn0 + 3];
      }
      *(float4*)(Cp + (size_t)(gm0 + i) * ldc + gn0) = r;
    }
  }
}

// ---------------- host launch ----------------

extern "C" void kernel_launch(void* const* d_in, const int* in_sizes, int n_in,
                              void* d_out, int out_size, void* d_ws, size_t ws_size,
                              hipStream_t stream) {
  const float* x     = (const float*)d_in[0];
  const float* u     = (const float*)d_in[1];
  const float* ln1_w = (const float*)d_in[2];
  const float* ln1_b = (const float*)d_in[3];
  const float* ln2_w = (const float*)d_in[4];
  const float* ln2_b = (const float*)d_in[5];
  const float* wq    = (const float*)d_in[6];
  const float* wk    = (const float*)d_in[7];
  const float* wv    = (const float*)d_in[8];
  const float* wo    = (const float*)d_in[9];
  const float* bo    = (const float*)d_in[10];
  const float* u_w   = (const float*)d_in[11];
  const float* u_b   = (const float*)d_in[12];
  const float* rms_w = (const float*)d_in[13];
  const float* w1    = (const float*)d_in[14];
  const float* b1    = (const float*)d_in[15];
  const float* w2    = (const float*)d_in[16];
  const float* b2    = (const float*)d_in[17];

  float* out   = (float*)d_out;
  float* attnW = out + (size_t)Bb * Nn * Dd;  // second output: [B,H,N,N]

  const size_t RSZ  = (size_t)Bb * Nn * Dd;  // 4194304 floats
  const size_t RSZB = RSZ * 4;               // bytes
  char*  wsb  = (char*)d_ws;
  float* xn   = (float*)(wsb + 0 * RSZB);  // R0: xn -> ctx
  float* qb   = (float*)(wsb + 1 * RSZB);  // R1: q -> attn_out
  float* kb   = (float*)(wsb + 2 * RSZB);  // R2: k -> h
  float* vb   = (float*)(wsb + 3 * RSZB);  // R3: v -> {zbf, w1bf, w2bf}
  float* ctx  = xn;
  float* aout = qb;
  float* hbuf = kb;
  short* zbf  = (short*)(wsb + 3 * RSZB);
  short* w1bf = (short*)(wsb + 3 * RSZB + RSZB / 2);
  short* w2bf = w1bf + (size_t)DFFf * Dd;
  short* h1bf = (short*)(wsb + 4 * RSZB);

  const int MR = Bb * Nn;  // 8192 rows

  // 1. LayerNorm1
  ln1_kernel<<<MR, 256, 0, stream>>>(x, ln1_w, ln1_b, xn);

  // 2. Q,K,V projections (f32): [8192,512] = xn @ W^T
  dim3 gProj(Dd / 64, MR / 128, 1);
  gemm_kernel<128,64,16,8,4,0,0><<<gProj,256,0,stream>>>(
      xn, wq, qb, nullptr, nullptr, nullptr, MR, Dd, Dd, Dd, Dd, Dd, 1.f);
  gemm_kernel<128,64,16,8,4,0,0><<<gProj,256,0,stream>>>(
      xn, wk, kb, nullptr, nullptr, nullptr, MR, Dd, Dd, Dd, Dd, Dd, 1.f);
  gemm_kernel<128,64,16,8,4,0,0><<<gProj,256,0,stream>>>(
      xn, wv, vb, nullptr, nullptr, nullptr, MR, Dd, Dd, Dd, Dd, Dd, 1.f);

  // 3. scores = 8 * q k^T + u-bias  -> attnW (raw scores)
  dim3 gSc(Nn / 64, Nn / 128, Bb * Hh);
  gemm_kernel<128,64,16,8,4,1,4><<<gSc,256,0,stream>>>(
      qb, kb, attnW, u_b, u, u_w, Nn, Nn, HDd, Dd, Dd, Nn, 8.f);

  // 4. softmax rows (in place)
  softmax_kernel<<<Bb * Hh * Nn, 256, 0, stream>>>(attnW);

  // 5. ctx = attn @ v (dedicated kernel)
  dim3 gCtx(Nn / 128, Bb * Hh);
  ctx_kernel<<<gCtx, 256, 0, stream>>>(attnW, vb, ctx);

  // 5b. convert FFN weights to bf16 (vb region dead after ctx)
  cvt_kernel<<<(DFFf * Dd / 4 + 255) / 256, 256, 0, stream>>>(w1, w1bf, DFFf * Dd / 4);
  cvt_kernel<<<(DFFf * Dd / 4 + 255) / 256, 256, 0, stream>>>(w2, w2bf, DFFf * Dd / 4);

  // 6. attn_out = ctx @ wo^T + bo
  gemm_kernel<128,64,16,8,4,0,1><<<gProj,256,0,stream>>>(
      ctx, wo, aout, bo, nullptr, nullptr, MR, Dd, Dd, Dd, Dd, Dd, 1.f);

  // 7. h = LN2(attn_out) + x ; zbf = bf16(RMSNorm(h))
  hz_kernel<<<MR, 256, 0, stream>>>(aout, x, ln2_w, ln2_b, rms_w, hbuf, zbf);

  // 8/9. FFN in bf16 MFMA, chunked over rows so h1bf fits
  size_t avail = ws_size > 4 * RSZB ? ws_size - 4 * RSZB : 0;
  int rows = MR;
  while (rows > 128 && (size_t)rows * DFFf * 2 > avail) rows >>= 1;
  for (int m0 = 0; m0 < MR; m0 += rows) {
    dim3 gF1(DFFf / 128, rows / 128);
    mfma_nt_kernel<128,128,0><<<gF1,256,0,stream>>>(
        zbf + (size_t)m0 * Dd, w1bf, h1bf, b1, nullptr, DFFf, Dd);
    dim3 gF2(Dd / 128, rows / 64);
    mfma_nt_kernel<64,128,1><<<gF2,256,0,stream>>>(
        h1bf, w2bf, out + (size_t)m0 * Dd, b2, hbuf + (size_t)m0 * Dd, Dd, DFFf);
  }
}

// Round 6
// 591.099 us; speedup vs baseline: 1.7391x; 1.0504x over previous
//
#include <hip/hip_runtime.h>
#include <math.h>

static constexpr int Bb  = 16;
static constexpr int Nn  = 512;
static constexpr int Dd  = 512;
static constexpr int Hh  = 8;
static constexpr int HDd = 64;
static constexpr int UEe = 6;
static constexpr int DFFf= 2048;

typedef __attribute__((ext_vector_type(8))) short short8v;
typedef __attribute__((ext_vector_type(4))) float f32x4;

__device__ __forceinline__ short f2bf(float f) {
  unsigned u = __float_as_uint(f);
  unsigned r = (u + 0x7fffu + ((u >> 16) & 1u)) >> 16;
  return (short)r;
}
__device__ __forceinline__ float bf2f(short h) {
  return __uint_as_float(((unsigned)(unsigned short)h) << 16);
}
__device__ __forceinline__ void split2(float v, short& hi, short& lo) {
  hi = f2bf(v);
  lo = f2bf(v - bf2f(hi));
}

// ---------------- block reduction helpers (256 threads, 4 waves) ----------------

__device__ __forceinline__ float2 block_sum2(float a, float b, float* sb) {
  #pragma unroll
  for (int o = 32; o; o >>= 1) { a += __shfl_down(a, o); b += __shfl_down(b, o); }
  const int lane = threadIdx.x & 63, wid = threadIdx.x >> 6;
  if (lane == 0) { sb[wid] = a; sb[4 + wid] = b; }
  __syncthreads();
  float ra = sb[0] + sb[1] + sb[2] + sb[3];
  float rb = sb[4] + sb[5] + sb[6] + sb[7];
  __syncthreads();
  return make_float2(ra, rb);
}

__device__ __forceinline__ float block_sum1(float a, float* sb) {
  #pragma unroll
  for (int o = 32; o; o >>= 1) a += __shfl_down(a, o);
  const int lane = threadIdx.x & 63, wid = threadIdx.x >> 6;
  if (lane == 0) sb[wid] = a;
  __syncthreads();
  float ra = sb[0] + sb[1] + sb[2] + sb[3];
  __syncthreads();
  return ra;
}

// ---------------- LayerNorm on x -> xn (split bf16 hi/lo) ----------------

__global__ __launch_bounds__(256) void ln1_kernel(
    const float* __restrict__ x, const float* __restrict__ w,
    const float* __restrict__ b, short* __restrict__ oh, short* __restrict__ ol) {
  __shared__ float sb[8];
  const size_t row = blockIdx.x;
  const int t = threadIdx.x;
  const float* xr = x + row * Dd;
  float2 xv = *(const float2*)(xr + 2 * t);
  float2 r = block_sum2(xv.x + xv.y, xv.x * xv.x + xv.y * xv.y, sb);
  const float mu = r.x * (1.f / Dd);
  const float var = r.y * (1.f / Dd) - mu * mu;
  const float rstd = rsqrtf(var + 1e-5f);
  float2 wv = *(const float2*)(w + 2 * t);
  float2 bv = *(const float2*)(b + 2 * t);
  float v0 = (xv.x - mu) * rstd * wv.x + bv.x;
  float v1 = (xv.y - mu) * rstd * wv.y + bv.y;
  short2 h2, l2;
  split2(v0, h2.x, l2.x);
  split2(v1, h2.y, l2.y);
  *(short2*)(oh + row * Dd + 2 * t) = h2;
  *(short2*)(ol + row * Dd + 2 * t) = l2;
}

// ------- LN2(attn_out)+residual -> h (f32) ; RMSNorm(h) -> zbf (bf16) -------

__global__ __launch_bounds__(256) void hz_kernel(
    const float* __restrict__ ao, const float* __restrict__ xres,
    const float* __restrict__ w, const float* __restrict__ b,
    const float* __restrict__ rw,
    float* __restrict__ h, short* __restrict__ zbf) {
  __shared__ float sb[8];
  const size_t row = blockIdx.x;
  const int t = threadIdx.x;
  float2 av = *(const float2*)(ao + row * Dd + 2 * t);
  float2 r = block_sum2(av.x + av.y, av.x * av.x + av.y * av.y, sb);
  const float mu = r.x * (1.f / Dd);
  const float var = r.y * (1.f / Dd) - mu * mu;
  const float rstd = rsqrtf(var + 1e-5f);
  float2 wv = *(const float2*)(w + 2 * t);
  float2 bv = *(const float2*)(b + 2 * t);
  float2 xv = *(const float2*)(xres + row * Dd + 2 * t);
  float2 hv;
  hv.x = (av.x - mu) * rstd * wv.x + bv.x + xv.x;
  hv.y = (av.y - mu) * rstd * wv.y + bv.y + xv.y;
  *(float2*)(h + row * Dd + 2 * t) = hv;
  float ms = block_sum1(hv.x * hv.x + hv.y * hv.y, sb) * (1.f / Dd);
  const float rr = rsqrtf(ms + 1.1920929e-07f);
  float2 rwv = *(const float2*)(rw + 2 * t);
  short2 zv;
  zv.x = f2bf(hv.x * rr * rwv.x);
  zv.y = f2bf(hv.y * rr * rwv.y);
  *(short2*)(zbf + row * Dd + 2 * t) = zv;
}

// ---------------- f32 -> bf16 converts ----------------

__global__ __launch_bounds__(256) void cvt_kernel(
    const float* __restrict__ in, short* __restrict__ out, int n4) {
  int i = blockIdx.x * 256 + threadIdx.x;
  if (i < n4) {
    float4 v = ((const float4*)in)[i];
    short4 o;
    o.x = f2bf(v.x); o.y = f2bf(v.y); o.z = f2bf(v.z); o.w = f2bf(v.w);
    ((short4*)out)[i] = o;
  }
}

__global__ __launch_bounds__(256) void cvt2_kernel(
    const float* __restrict__ in, short* __restrict__ hi,
    short* __restrict__ lo, int n4) {
  int i = blockIdx.x * 256 + threadIdx.x;
  if (i < n4) {
    float4 v = ((const float4*)in)[i];
    short4 h, l;
    split2(v.x, h.x, l.x); split2(v.y, h.y, l.y);
    split2(v.z, h.z, l.z); split2(v.w, h.w, l.w);
    ((short4*)hi)[i] = h;
    ((short4*)lo)[i] = l;
  }
}

// -------- V transpose: v[8192][512] bf16 -> vT[b][h][hd(64)][n(512)] bf16 --------

__global__ __launch_bounds__(256) void vt_kernel(
    const short* __restrict__ v, short* __restrict__ vT) {
  __shared__ short Lt[64][72];
  const int z = blockIdx.y, b = z >> 3, hh = z & 7;
  const int n0 = blockIdx.x * 64;
  const int tid = threadIdx.x;
  #pragma unroll
  for (int it = 0; it < 2; ++it) {
    int id = tid + it * 256;
    int r = id >> 3, c8 = id & 7;
    *(short8v*)&Lt[r][c8 * 8] =
        *(const short8v*)(v + ((size_t)(b * Nn + n0 + r)) * Dd + hh * HDd + c8 * 8);
  }
  __syncthreads();
  #pragma unroll
  for (int it = 0; it < 2; ++it) {
    int id = tid + it * 256;
    int c = id >> 3, r8 = id & 7;
    short8v g;
    #pragma unroll
    for (int k = 0; k < 8; ++k) g[k] = Lt[r8 * 8 + k][c];
    *(short8v*)(vT + ((size_t)z * HDd + c) * Nn + n0 + r8 * 8) = g;
  }
}

// ------ 3-term split-bf16 NT GEMM: C = (Ah+Al)@(Wh+Wl)^T (lo*lo dropped) ------
// BM=128, BN=64, 256 threads, 2x2 waves, wave tile 64x32. BK=32.
// EPI 0: split-write bf16 hi->C1, lo->C2. EPI 1: f32 acc+bias -> C1. EPI 2: bf16 hi -> C1.

template <int EPI>
__global__ __launch_bounds__(256) void mfma_nt3_kernel(
    const short* __restrict__ Ah, const short* __restrict__ Al,
    const short* __restrict__ Wh, const short* __restrict__ Wl,
    void* __restrict__ C1, void* __restrict__ C2,
    const float* __restrict__ bias, int Nc, int K) {
  constexpr int BM = 128, BN = 64;
  constexpr int MREP = 4, NREP = 2;
  __shared__ short Ash[BM][40], Asl[BM][40], Bsh[BN][40], Bsl[BN][40];
  const int tid = threadIdx.x;
  const int wave = tid >> 6, lane = tid & 63;
  const int wr = wave >> 1, wc = wave & 1;
  const int lrow = lane & 15, kblk = lane >> 4;
  const size_t bm = (size_t)blockIdx.y * BM, bn = (size_t)blockIdx.x * BN;
  f32x4 acc[MREP][NREP] = {};
  for (int k0 = 0; k0 < K; k0 += 32) {
    __syncthreads();
    #pragma unroll
    for (int it = 0; it < 2; ++it) {
      int id = tid + it * 256;
      int r = id >> 2, kq = id & 3;
      const size_t go = (bm + r) * K + k0 + kq * 8;
      *(short8v*)&Ash[r][kq * 8] = *(const short8v*)(Ah + go);
      *(short8v*)&Asl[r][kq * 8] = *(const short8v*)(Al + go);
    }
    {
      int r = tid >> 2, kq = tid & 3;
      const size_t go = (bn + r) * K + k0 + kq * 8;
      *(short8v*)&Bsh[r][kq * 8] = *(const short8v*)(Wh + go);
      *(short8v*)&Bsl[r][kq * 8] = *(const short8v*)(Wl + go);
    }
    __syncthreads();
    short8v afh[MREP], afl[MREP], bfh[NREP], bfl[NREP];
    #pragma unroll
    for (int i = 0; i < MREP; ++i) {
      afh[i] = *(const short8v*)&Ash[wr * 64 + i * 16 + lrow][kblk * 8];
      afl[i] = *(const short8v*)&Asl[wr * 64 + i * 16 + lrow][kblk * 8];
    }
    #pragma unroll
    for (int j = 0; j < NREP; ++j) {
      bfh[j] = *(const short8v*)&Bsh[wc * 32 + j * 16 + lrow][kblk * 8];
      bfl[j] = *(const short8v*)&Bsl[wc * 32 + j * 16 + lrow][kblk * 8];
    }
    #pragma unroll
    for (int i = 0; i < MREP; ++i)
      #pragma unroll
      for (int j = 0; j < NREP; ++j) {
        acc[i][j] = __builtin_amdgcn_mfma_f32_16x16x32_bf16(afh[i], bfh[j], acc[i][j], 0, 0, 0);
        acc[i][j] = __builtin_amdgcn_mfma_f32_16x16x32_bf16(afl[i], bfh[j], acc[i][j], 0, 0, 0);
        acc[i][j] = __builtin_amdgcn_mfma_f32_16x16x32_bf16(afh[i], bfl[j], acc[i][j], 0, 0, 0);
      }
  }
  #pragma unroll
  for (int i = 0; i < MREP; ++i) {
    #pragma unroll
    for (int j = 0; j < NREP; ++j) {
      const size_t gcol = bn + wc * 32 + j * 16 + lrow;
      float bb = 0.f;
      if constexpr (EPI == 1) bb = bias[gcol];
      #pragma unroll
      for (int reg = 0; reg < 4; ++reg) {
        const size_t grow = bm + wr * 64 + i * 16 + kblk * 4 + reg;
        float vv = acc[i][j][reg] + bb;
        if constexpr (EPI == 0) {
          short hh_, ll_;
          split2(vv, hh_, ll_);
          ((short*)C1)[grow * Nc + gcol] = hh_;
          ((short*)C2)[grow * Nc + gcol] = ll_;
        } else if constexpr (EPI == 1) {
          ((float*)C1)[grow * Nc + gcol] = vv;
        } else {
          ((short*)C1)[grow * Nc + gcol] = f2bf(vv);
        }
      }
    }
  }
}

// -------- scores: S = 8*(q k^T) + u-bias, per head, 3-term split bf16 --------
// grid (Nn/64 j-tiles, Nn/128 i-tiles, B*H). 256 threads, 2x2 waves.

__global__ __launch_bounds__(256) void scores3_kernel(
    const short* __restrict__ qh, const short* __restrict__ ql,
    const short* __restrict__ kh, const short* __restrict__ kl,
    float* __restrict__ S, const float* __restrict__ u,
    const float* __restrict__ u_w, const float* __restrict__ u_b) {
  constexpr int MREP = 4, NREP = 2;
  __shared__ short Qsh[128][40], Qsl[128][40], Ksh[64][40], Ksl[64][40];
  const int z = blockIdx.z, b = z >> 3, hh = z & 7;
  const int tid = threadIdx.x;
  const short* Qph = qh + ((size_t)b * Nn + blockIdx.y * 128) * Dd + hh * HDd;
  const short* Qpl = ql + ((size_t)b * Nn + blockIdx.y * 128) * Dd + hh * HDd;
  const short* Kph = kh + ((size_t)b * Nn + blockIdx.x * 64) * Dd + hh * HDd;
  const short* Kpl = kl + ((size_t)b * Nn + blockIdx.x * 64) * Dd + hh * HDd;
  const int wave = tid >> 6, lane = tid & 63;
  const int wr = wave >> 1, wc = wave & 1;
  const int lrow = lane & 15, kblk = lane >> 4;
  f32x4 acc[MREP][NREP] = {};
  #pragma unroll
  for (int k0 = 0; k0 < HDd; k0 += 32) {
    __syncthreads();
    #pragma unroll
    for (int it = 0; it < 2; ++it) {
      int id = tid + it * 256;
      int r = id >> 2, kq = id & 3;
      const size_t go = (size_t)r * Dd + k0 + kq * 8;
      *(short8v*)&Qsh[r][kq * 8] = *(const short8v*)(Qph + go);
      *(short8v*)&Qsl[r][kq * 8] = *(const short8v*)(Qpl + go);
    }
    {
      int r = tid >> 2, kq = tid & 3;
      const size_t go = (size_t)r * Dd + k0 + kq * 8;
      *(short8v*)&Ksh[r][kq * 8] = *(const short8v*)(Kph + go);
      *(short8v*)&Ksl[r][kq * 8] = *(const short8v*)(Kpl + go);
    }
    __syncthreads();
    short8v afh[MREP], afl[MREP], bfh[NREP], bfl[NREP];
    #pragma unroll
    for (int i = 0; i < MREP; ++i) {
      afh[i] = *(const short8v*)&Qsh[wr * 64 + i * 16 + lrow][kblk * 8];
      afl[i] = *(const short8v*)&Qsl[wr * 64 + i * 16 + lrow][kblk * 8];
    }
    #pragma unroll
    for (int j = 0; j < NREP; ++j) {
      bfh[j] = *(const short8v*)&Ksh[wc * 32 + j * 16 + lrow][kblk * 8];
      bfl[j] = *(const short8v*)&Ksl[wc * 32 + j * 16 + lrow][kblk * 8];
    }
    #pragma unroll
    for (int i = 0; i < MREP; ++i)
      #pragma unroll
      for (int j = 0; j < NREP; ++j) {
        acc[i][j] = __builtin_amdgcn_mfma_f32_16x16x32_bf16(afh[i], bfh[j], acc[i][j], 0, 0, 0);
        acc[i][j] = __builtin_amdgcn_mfma_f32_16x16x32_bf16(afl[i], bfh[j], acc[i][j], 0, 0, 0);
        acc[i][j] = __builtin_amdgcn_mfma_f32_16x16x32_bf16(afh[i], bfl[j], acc[i][j], 0, 0, 0);
      }
  }
  const float* ub_ = u + (size_t)b * UEe * Nn * Nn;
  float uw[UEe];
  #pragma unroll
  for (int c = 0; c < UEe; ++c) uw[c] = u_w[hh * UEe + c];
  const float ub = u_b[hh];
  float* Sp = S + (size_t)z * Nn * Nn;
  #pragma unroll
  for (int i = 0; i < MREP; ++i) {
    #pragma unroll
    for (int j = 0; j < NREP; ++j) {
      const int gcol = blockIdx.x * 64 + wc * 32 + j * 16 + lrow;
      #pragma unroll
      for (int reg = 0; reg < 4; ++reg) {
        const int grow = blockIdx.y * 128 + wr * 64 + i * 16 + kblk * 4 + reg;
        const size_t off = (size_t)grow * Nn + gcol;
        float v = 8.f * acc[i][j][reg] + ub;
        #pragma unroll
        for (int c = 0; c < UEe; ++c)
          v = fmaf(uw[c], ub_[(size_t)c * Nn * Nn + off], v);
        Sp[off] = v;
      }
    }
  }
}

// -------- fused softmax + P write + P@V -> ctx (split bf16 out) --------
// grid (16 row-tiles of 32, 128 z). 256 threads. In-place S->P in attnW.

__global__ __launch_bounds__(256) void smctx_kernel(
    float* __restrict__ P, const short* __restrict__ vT,
    short* __restrict__ ctxh, short* __restrict__ ctxl) {
  __shared__ short Ps[32][520];
  __shared__ short Bs[64][136];
  const int z = blockIdx.y, b = z >> 3, hh = z & 7;
  const int row0 = blockIdx.x * 32;
  const int tid = threadIdx.x;
  const int lr = tid >> 3, sub = tid & 7;
  float* Sp = P + (size_t)z * Nn * Nn + (size_t)(row0 + lr) * Nn + sub * 64;
  float4 s[16];
  #pragma unroll
  for (int q = 0; q < 16; ++q) s[q] = *(const float4*)(Sp + q * 4);
  float m = -1e30f;
  #pragma unroll
  for (int q = 0; q < 16; ++q)
    m = fmaxf(m, fmaxf(fmaxf(s[q].x, s[q].y), fmaxf(s[q].z, s[q].w)));
  m = fmaxf(m, __shfl_xor(m, 1));
  m = fmaxf(m, __shfl_xor(m, 2));
  m = fmaxf(m, __shfl_xor(m, 4));
  float sum = 0.f;
  #pragma unroll
  for (int q = 0; q < 16; ++q) {
    s[q].x = __expf(s[q].x - m); s[q].y = __expf(s[q].y - m);
    s[q].z = __expf(s[q].z - m); s[q].w = __expf(s[q].w - m);
    sum += (s[q].x + s[q].y) + (s[q].z + s[q].w);
  }
  sum += __shfl_xor(sum, 1);
  sum += __shfl_xor(sum, 2);
  sum += __shfl_xor(sum, 4);
  const float rr = 1.f / sum;
  #pragma unroll
  for (int q = 0; q < 16; ++q) {
    s[q].x *= rr; s[q].y *= rr; s[q].z *= rr; s[q].w *= rr;
    *(float4*)(Sp + q * 4) = s[q];
  }
  #pragma unroll
  for (int q = 0; q < 8; ++q) {
    float4 a = s[2 * q], c = s[2 * q + 1];
    short8v pk;
    pk[0] = f2bf(a.x); pk[1] = f2bf(a.y); pk[2] = f2bf(a.z); pk[3] = f2bf(a.w);
    pk[4] = f2bf(c.x); pk[5] = f2bf(c.y); pk[6] = f2bf(c.z); pk[7] = f2bf(c.w);
    *(short8v*)&Ps[lr][sub * 64 + q * 8] = pk;
  }
  // ---- PV MFMA: ctx_tile[32][64] = P_tile[32][512] @ V[512][64] ----
  const int wave = tid >> 6, lane = tid & 63;
  const int wr = wave >> 1, wc = wave & 1;
  const int lrow = lane & 15, kblk = lane >> 4;
  f32x4 acc0 = {}, acc1 = {};
  for (int kc = 0; kc < 4; ++kc) {
    __syncthreads();
    #pragma unroll
    for (int it = 0; it < 4; ++it) {
      int id = tid + it * 256;
      int rrow = id >> 4, k8 = id & 15;
      *(short8v*)&Bs[rrow][k8 * 8] =
          *(const short8v*)(vT + ((size_t)z * HDd + rrow) * Nn + kc * 128 + k8 * 8);
    }
    __syncthreads();
    #pragma unroll
    for (int ks = 0; ks < 4; ++ks) {
      short8v af = *(const short8v*)&Ps[wr * 16 + lrow][kc * 128 + ks * 32 + kblk * 8];
      short8v b0 = *(const short8v*)&Bs[wc * 32 + lrow][ks * 32 + kblk * 8];
      short8v b1 = *(const short8v*)&Bs[wc * 32 + 16 + lrow][ks * 32 + kblk * 8];
      acc0 = __builtin_amdgcn_mfma_f32_16x16x32_bf16(af, b0, acc0, 0, 0, 0);
      acc1 = __builtin_amdgcn_mfma_f32_16x16x32_bf16(af, b1, acc1, 0, 0, 0);
    }
  }
  const size_t outbase =
      ((size_t)(b * Nn + row0 + wr * 16 + kblk * 4)) * Dd + hh * HDd + wc * 32 + lrow;
  #pragma unroll
  for (int reg = 0; reg < 4; ++reg) {
    short h0, l0, h1, l1;
    split2(acc0[reg], h0, l0);
    split2(acc1[reg], h1, l1);
    ctxh[outbase + (size_t)reg * Dd] = h0;
    ctxl[outbase + (size_t)reg * Dd] = l0;
    ctxh[outbase + (size_t)reg * Dd + 16] = h1;
    ctxl[outbase + (size_t)reg * Dd + 16] = l1;
  }
}

// ---------------- bf16 MFMA NT GEMM (FFN): C[M,Nc] = A[M,K] @ W[Nc,K]^T ----------------
// EPI 0: silu(acc+bias)->bf16. 1: acc+bias+res->f32.

template <int BM, int BN, int EPI>
__global__ __launch_bounds__(256) void mfma_nt_kernel(
    const short* __restrict__ Ag, const short* __restrict__ Wg,
    void* __restrict__ Cv, const float* __restrict__ bias,
    const float* __restrict__ res, int Nc, int K) {
  constexpr int MREP = BM / 32, NREP = BN / 32;
  __shared__ short As[BM][72];
  __shared__ short Bs[BN][72];
  const int tid = threadIdx.x;
  const int wave = tid >> 6, lane = tid & 63;
  const int wr = wave >> 1, wc = wave & 1;
  const int lrow = lane & 15, kblk = lane >> 4;
  const size_t bm = (size_t)blockIdx.y * BM, bn = (size_t)blockIdx.x * BN;
  f32x4 acc[MREP][NREP] = {};
  for (int k0 = 0; k0 < K; k0 += 32) {
    __syncthreads();
    #pragma unroll
    for (int it = 0; it < BM / 64; ++it) {
      int id = tid + it * 256;
      int r = id >> 2, kq = id & 3;
      *(short8v*)&As[r][kq * 8] = *(const short8v*)(Ag + (bm + r) * K + k0 + kq * 8);
    }
    #pragma unroll
    for (int it = 0; it < BN / 64; ++it) {
      int id = tid + it * 256;
      int r = id >> 2, kq = id & 3;
      *(short8v*)&Bs[r][kq * 8] = *(const short8v*)(Wg + (bn + r) * K + k0 + kq * 8);
    }
    __syncthreads();
    short8v af[MREP], bf[NREP];
    #pragma unroll
    for (int i = 0; i < MREP; ++i)
      af[i] = *(const short8v*)&As[wr * (BM / 2) + i * 16 + lrow][kblk * 8];
    #pragma unroll
    for (int j = 0; j < NREP; ++j)
      bf[j] = *(const short8v*)&Bs[wc * (BN / 2) + j * 16 + lrow][kblk * 8];
    #pragma unroll
    for (int i = 0; i < MREP; ++i)
      #pragma unroll
      for (int j = 0; j < NREP; ++j)
        acc[i][j] = __builtin_amdgcn_mfma_f32_16x16x32_bf16(af[i], bf[j], acc[i][j], 0, 0, 0);
  }
  #pragma unroll
  for (int i = 0; i < MREP; ++i) {
    #pragma unroll
    for (int j = 0; j < NREP; ++j) {
      const size_t gcol = bn + wc * (BN / 2) + j * 16 + lrow;
      const float bb = bias[gcol];
      #pragma unroll
      for (int reg = 0; reg < 4; ++reg) {
        const size_t grow = bm + wr * (BM / 2) + i * 16 + kblk * 4 + reg;
        float vv = acc[i][j][reg] + bb;
        if constexpr (EPI == 0) {
          vv = vv / (1.f + __expf(-vv));
          ((short*)Cv)[grow * Nc + gcol] = f2bf(vv);
        } else {
          ((float*)Cv)[grow * Nc + gcol] = vv + res[grow * Nc + gcol];
        }
      }
    }
  }
}

// ---------------- host launch ----------------

extern "C" void kernel_launch(void* const* d_in, const int* in_sizes, int n_in,
                              void* d_out, int out_size, void* d_ws, size_t ws_size,
                              hipStream_t stream) {
  const float* x     = (const float*)d_in[0];
  const float* u     = (const float*)d_in[1];
  const float* ln1_w = (const float*)d_in[2];
  const float* ln1_b = (const float*)d_in[3];
  const float* ln2_w = (const float*)d_in[4];
  const float* ln2_b = (const float*)d_in[5];
  const float* wq    = (const float*)d_in[6];
  const float* wk    = (const float*)d_in[7];
  const float* wv    = (const float*)d_in[8];
  const float* wo    = (const float*)d_in[9];
  const float* bo    = (const float*)d_in[10];
  const float* u_w   = (const float*)d_in[11];
  const float* u_b   = (const float*)d_in[12];
  const float* rms_w = (const float*)d_in[13];
  const float* w1    = (const float*)d_in[14];
  const float* b1    = (const float*)d_in[15];
  const float* w2    = (const float*)d_in[16];
  const float* b2    = (const float*)d_in[17];

  float* out   = (float*)d_out;
  float* attnW = out + (size_t)Bb * Nn * Dd;  // second output: [B,H,N,N]

  const size_t SB = (size_t)Bb * Nn * Dd * 2;  // 8 MB (one bf16 activation buffer)
  char* wsb = (char*)d_ws;
  // slot map (8 MB each):
  // 0: xnh -> vTh -> zbf | 1: xnl -> ctxh -> h1bf | 2: qh -> aout[0:8MB]
  // 3: ql -> aout[8:16MB] | 4: kh -> hbuf[0:8MB] | 5: kl -> hbuf[8:16MB]
  // 6: vh -> ctxl
  short* xnh  = (short*)(wsb + 0 * SB);
  short* xnl  = (short*)(wsb + 1 * SB);
  short* qh   = (short*)(wsb + 2 * SB);
  short* ql   = (short*)(wsb + 3 * SB);
  short* kh   = (short*)(wsb + 4 * SB);
  short* kl   = (short*)(wsb + 5 * SB);
  short* vh   = (short*)(wsb + 6 * SB);
  short* vTh  = (short*)(wsb + 0 * SB);
  short* ctxh = (short*)(wsb + 1 * SB);
  short* ctxl = (short*)(wsb + 6 * SB);
  float* aout = (float*)(wsb + 2 * SB);
  float* hbuf = (float*)(wsb + 4 * SB);
  short* zbf  = (short*)(wsb + 0 * SB);
  short* h1bf = (short*)(wsb + 1 * SB);
  const size_t WTBYTES = 8 * (size_t)Dd * Dd * 2 + 2 * (size_t)DFFf * Dd * 2;  // 8 MB
  const size_t wt = (ws_size - WTBYTES) & ~(size_t)255;
  short* wqh = (short*)(wsb + wt);
  short* wql = wqh + (size_t)Dd * Dd;
  short* wkh = wql + (size_t)Dd * Dd;
  short* wkl = wkh + (size_t)Dd * Dd;
  short* wvh = wkl + (size_t)Dd * Dd;
  short* wvl = wvh + (size_t)Dd * Dd;
  short* woh = wvl + (size_t)Dd * Dd;
  short* wol = woh + (size_t)Dd * Dd;
  short* w1h = wol + (size_t)Dd * Dd;
  short* w2h = w1h + (size_t)DFFf * Dd;

  const int MR = Bb * Nn;  // 8192 rows

  // 0. weight converts
  cvt2_kernel<<<256, 256, 0, stream>>>(wq, wqh, wql, Dd * Dd / 4);
  cvt2_kernel<<<256, 256, 0, stream>>>(wk, wkh, wkl, Dd * Dd / 4);
  cvt2_kernel<<<256, 256, 0, stream>>>(wv, wvh, wvl, Dd * Dd / 4);
  cvt2_kernel<<<256, 256, 0, stream>>>(wo, woh, wol, Dd * Dd / 4);
  cvt_kernel<<<1024, 256, 0, stream>>>(w1, w1h, DFFf * Dd / 4);
  cvt_kernel<<<1024, 256, 0, stream>>>(w2, w2h, DFFf * Dd / 4);

  // 1. LayerNorm1 -> split bf16
  ln1_kernel<<<MR, 256, 0, stream>>>(x, ln1_w, ln1_b, xnh, xnl);

  // 2. Q,K,V projections (3-term split MFMA)
  dim3 gProj(Dd / 64, MR / 128);
  mfma_nt3_kernel<0><<<gProj,256,0,stream>>>(xnh, xnl, wqh, wql, qh, ql, nullptr, Dd, Dd);
  mfma_nt3_kernel<0><<<gProj,256,0,stream>>>(xnh, xnl, wkh, wkl, kh, kl, nullptr, Dd, Dd);
  mfma_nt3_kernel<2><<<gProj,256,0,stream>>>(xnh, xnl, wvh, wvl, vh, nullptr, nullptr, Dd, Dd);

  // 3. V transpose per head
  dim3 gVt(Nn / 64, Bb * Hh);
  vt_kernel<<<gVt, 256, 0, stream>>>(vh, vTh);

  // 4. scores = 8 q k^T + u-bias -> attnW (raw S, f32), 3-term
  dim3 gSc(Nn / 64, Nn / 128, Bb * Hh);
  scores3_kernel<<<gSc, 256, 0, stream>>>(qh, ql, kh, kl, attnW, u, u_w, u_b);

  // 5. fused softmax (in-place P) + P@V -> ctx split bf16
  dim3 gSm(Nn / 32, Bb * Hh);
  smctx_kernel<<<gSm, 256, 0, stream>>>(attnW, vTh, ctxh, ctxl);

  // 6. attn_out = ctx @ wo^T + bo (3-term, f32 out)
  mfma_nt3_kernel<1><<<gProj,256,0,stream>>>(ctxh, ctxl, woh, wol, aout, nullptr, bo, Dd, Dd);

  // 7. h = LN2(attn_out) + x ; zbf = bf16(RMSNorm(h))
  hz_kernel<<<MR, 256, 0, stream>>>(aout, x, ln2_w, ln2_b, rms_w, hbuf, zbf);

  // 8/9. FFN bf16 MFMA, 4 chunks of 2048 rows (h1bf = one 8MB slot)
  const int rows = 2048;
  for (int m0 = 0; m0 < MR; m0 += rows) {
    dim3 gF1(DFFf / 128, rows / 128);
    mfma_nt_kernel<128,128,0><<<gF1,256,0,stream>>>(
        zbf + (size_t)m0 * Dd, w1h, h1bf, b1, nullptr, DFFf, Dd);
    dim3 gF2(Dd / 128, rows / 64);
    mfma_nt_kernel<64,128,1><<<gF2,256,0,stream>>>(
        h1bf, w2h, out + (size_t)m0 * Dd, b2, hbuf + (size_t)m0 * Dd, Dd, DFFf);
  }
}

// Round 7
// 555.796 us; speedup vs baseline: 1.8496x; 1.0635x over previous
//
#include <hip/hip_runtime.h>
#include <math.h>

static constexpr int Bb  = 16;
static constexpr int Nn  = 512;
static constexpr int Dd  = 512;
static constexpr int Hh  = 8;
static constexpr int HDd = 64;
static constexpr int UEe = 6;
static constexpr int DFFf= 2048;

typedef __attribute__((ext_vector_type(8))) short short8v;
typedef __attribute__((ext_vector_type(4))) float f32x4;

__device__ __forceinline__ short f2bf(float f) {
  unsigned u = __float_as_uint(f);
  unsigned r = (u + 0x7fffu + ((u >> 16) & 1u)) >> 16;
  return (short)r;
}
__device__ __forceinline__ float bf2f(short h) {
  return __uint_as_float(((unsigned)(unsigned short)h) << 16);
}
__device__ __forceinline__ void split2(float v, short& hi, short& lo) {
  hi = f2bf(v);
  lo = f2bf(v - bf2f(hi));
}

// ---------------- block reduction helpers (256 threads, 4 waves) ----------------

__device__ __forceinline__ float2 block_sum2(float a, float b, float* sb) {
  #pragma unroll
  for (int o = 32; o; o >>= 1) { a += __shfl_down(a, o); b += __shfl_down(b, o); }
  const int lane = threadIdx.x & 63, wid = threadIdx.x >> 6;
  if (lane == 0) { sb[wid] = a; sb[4 + wid] = b; }
  __syncthreads();
  float ra = sb[0] + sb[1] + sb[2] + sb[3];
  float rb = sb[4] + sb[5] + sb[6] + sb[7];
  __syncthreads();
  return make_float2(ra, rb);
}

__device__ __forceinline__ float block_sum1(float a, float* sb) {
  #pragma unroll
  for (int o = 32; o; o >>= 1) a += __shfl_down(a, o);
  const int lane = threadIdx.x & 63, wid = threadIdx.x >> 6;
  if (lane == 0) sb[wid] = a;
  __syncthreads();
  float ra = sb[0] + sb[1] + sb[2] + sb[3];
  __syncthreads();
  return ra;
}

// ---------------- LayerNorm on x -> xn (split bf16 hi/lo) ----------------

__global__ __launch_bounds__(256) void ln1_kernel(
    const float* __restrict__ x, const float* __restrict__ w,
    const float* __restrict__ b, short* __restrict__ oh, short* __restrict__ ol) {
  __shared__ float sb[8];
  const size_t row = blockIdx.x;
  const int t = threadIdx.x;
  const float* xr = x + row * Dd;
  float2 xv = *(const float2*)(xr + 2 * t);
  float2 r = block_sum2(xv.x + xv.y, xv.x * xv.x + xv.y * xv.y, sb);
  const float mu = r.x * (1.f / Dd);
  const float var = r.y * (1.f / Dd) - mu * mu;
  const float rstd = rsqrtf(var + 1e-5f);
  float2 wv = *(const float2*)(w + 2 * t);
  float2 bv = *(const float2*)(b + 2 * t);
  float v0 = (xv.x - mu) * rstd * wv.x + bv.x;
  float v1 = (xv.y - mu) * rstd * wv.y + bv.y;
  short2 h2, l2;
  split2(v0, h2.x, l2.x);
  split2(v1, h2.y, l2.y);
  *(short2*)(oh + row * Dd + 2 * t) = h2;
  *(short2*)(ol + row * Dd + 2 * t) = l2;
}

// ------- LN2(attn_out)+residual -> h (f32) ; RMSNorm(h) -> zbf (bf16) -------

__global__ __launch_bounds__(256) void hz_kernel(
    const float* __restrict__ ao, const float* __restrict__ xres,
    const float* __restrict__ w, const float* __restrict__ b,
    const float* __restrict__ rw,
    float* __restrict__ h, short* __restrict__ zbf) {
  __shared__ float sb[8];
  const size_t row = blockIdx.x;
  const int t = threadIdx.x;
  float2 av = *(const float2*)(ao + row * Dd + 2 * t);
  float2 r = block_sum2(av.x + av.y, av.x * av.x + av.y * av.y, sb);
  const float mu = r.x * (1.f / Dd);
  const float var = r.y * (1.f / Dd) - mu * mu;
  const float rstd = rsqrtf(var + 1e-5f);
  float2 wv = *(const float2*)(w + 2 * t);
  float2 bv = *(const float2*)(b + 2 * t);
  float2 xv = *(const float2*)(xres + row * Dd + 2 * t);
  float2 hv;
  hv.x = (av.x - mu) * rstd * wv.x + bv.x + xv.x;
  hv.y = (av.y - mu) * rstd * wv.y + bv.y + xv.y;
  *(float2*)(h + row * Dd + 2 * t) = hv;
  float ms = block_sum1(hv.x * hv.x + hv.y * hv.y, sb) * (1.f / Dd);
  const float rr = rsqrtf(ms + 1.1920929e-07f);
  float2 rwv = *(const float2*)(rw + 2 * t);
  short2 zv;
  zv.x = f2bf(hv.x * rr * rwv.x);
  zv.y = f2bf(hv.y * rr * rwv.y);
  *(short2*)(zbf + row * Dd + 2 * t) = zv;
}

// ---------------- f32 -> bf16 converts ----------------

__global__ __launch_bounds__(256) void cvt_kernel(
    const float* __restrict__ in, short* __restrict__ out, int n4) {
  int i = blockIdx.x * 256 + threadIdx.x;
  if (i < n4) {
    float4 v = ((const float4*)in)[i];
    short4 o;
    o.x = f2bf(v.x); o.y = f2bf(v.y); o.z = f2bf(v.z); o.w = f2bf(v.w);
    ((short4*)out)[i] = o;
  }
}

__global__ __launch_bounds__(256) void cvt2_kernel(
    const float* __restrict__ in, short* __restrict__ hi,
    short* __restrict__ lo, int n4) {
  int i = blockIdx.x * 256 + threadIdx.x;
  if (i < n4) {
    float4 v = ((const float4*)in)[i];
    short4 h, l;
    split2(v.x, h.x, l.x); split2(v.y, h.y, l.y);
    split2(v.z, h.z, l.z); split2(v.w, h.w, l.w);
    ((short4*)hi)[i] = h;
    ((short4*)lo)[i] = l;
  }
}

// -------- V transpose: v[8192][512] bf16 -> vT[b][h][hd(64)][n(512)] bf16 --------

__global__ __launch_bounds__(256) void vt_kernel(
    const short* __restrict__ v, short* __restrict__ vT) {
  __shared__ short Lt[64][72];
  const int z = blockIdx.y, b = z >> 3, hh = z & 7;
  const int n0 = blockIdx.x * 64;
  const int tid = threadIdx.x;
  #pragma unroll
  for (int it = 0; it < 2; ++it) {
    int id = tid + it * 256;
    int r = id >> 3, c8 = id & 7;
    *(short8v*)&Lt[r][c8 * 8] =
        *(const short8v*)(v + ((size_t)(b * Nn + n0 + r)) * Dd + hh * HDd + c8 * 8);
  }
  __syncthreads();
  #pragma unroll
  for (int it = 0; it < 2; ++it) {
    int id = tid + it * 256;
    int c = id >> 3, r8 = id & 7;
    short8v g;
    #pragma unroll
    for (int k = 0; k < 8; ++k) g[k] = Lt[r8 * 8 + k][c];
    *(short8v*)(vT + ((size_t)z * HDd + c) * Nn + n0 + r8 * 8) = g;
  }
}

// ------ merged QKV 3-term split-bf16 NT GEMM ------
// W is concatenated [1536][512] (q rows 0-511, k 512-1023, v 1024-1535).
// BM=128, BN=64 -> each block entirely within one segment. K=512.

__global__ __launch_bounds__(256) void mfma_qkv3_kernel(
    const short* __restrict__ Ah, const short* __restrict__ Al,
    const short* __restrict__ Wh, const short* __restrict__ Wl,
    short* __restrict__ qh_, short* __restrict__ ql_,
    short* __restrict__ kh_, short* __restrict__ kl_,
    short* __restrict__ vh_) {
  constexpr int MREP = 4, NREP = 2;
  __shared__ short Ash[128][40], Asl[128][40], Bsh[64][40], Bsl[64][40];
  const int tid = threadIdx.x;
  const int wave = tid >> 6, lane = tid & 63;
  const int wr = wave >> 1, wc = wave & 1;
  const int lrow = lane & 15, kblk = lane >> 4;
  const size_t bm = (size_t)blockIdx.y * 128, bn = (size_t)blockIdx.x * 64;
  f32x4 acc[MREP][NREP] = {};
  for (int k0 = 0; k0 < Dd; k0 += 32) {
    __syncthreads();
    #pragma unroll
    for (int it = 0; it < 2; ++it) {
      int id = tid + it * 256;
      int r = id >> 2, kq = id & 3;
      const size_t go = (bm + r) * Dd + k0 + kq * 8;
      *(short8v*)&Ash[r][kq * 8] = *(const short8v*)(Ah + go);
      *(short8v*)&Asl[r][kq * 8] = *(const short8v*)(Al + go);
    }
    {
      int r = tid >> 2, kq = tid & 3;
      const size_t go = (bn + r) * Dd + k0 + kq * 8;
      *(short8v*)&Bsh[r][kq * 8] = *(const short8v*)(Wh + go);
      *(short8v*)&Bsl[r][kq * 8] = *(const short8v*)(Wl + go);
    }
    __syncthreads();
    short8v afh[MREP], afl[MREP], bfh[NREP], bfl[NREP];
    #pragma unroll
    for (int i = 0; i < MREP; ++i) {
      afh[i] = *(const short8v*)&Ash[wr * 64 + i * 16 + lrow][kblk * 8];
      afl[i] = *(const short8v*)&Asl[wr * 64 + i * 16 + lrow][kblk * 8];
    }
    #pragma unroll
    for (int j = 0; j < NREP; ++j) {
      bfh[j] = *(const short8v*)&Bsh[wc * 32 + j * 16 + lrow][kblk * 8];
      bfl[j] = *(const short8v*)&Bsl[wc * 32 + j * 16 + lrow][kblk * 8];
    }
    #pragma unroll
    for (int i = 0; i < MREP; ++i)
      #pragma unroll
      for (int j = 0; j < NREP; ++j) {
        acc[i][j] = __builtin_amdgcn_mfma_f32_16x16x32_bf16(afh[i], bfh[j], acc[i][j], 0, 0, 0);
        acc[i][j] = __builtin_amdgcn_mfma_f32_16x16x32_bf16(afl[i], bfh[j], acc[i][j], 0, 0, 0);
        acc[i][j] = __builtin_amdgcn_mfma_f32_16x16x32_bf16(afh[i], bfl[j], acc[i][j], 0, 0, 0);
      }
  }
  const int seg = (int)(bn >> 9);  // uniform per block
  short* dsth = seg == 0 ? qh_ : (seg == 1 ? kh_ : vh_);
  short* dstl = seg == 0 ? ql_ : kl_;
  #pragma unroll
  for (int i = 0; i < MREP; ++i) {
    #pragma unroll
    for (int j = 0; j < NREP; ++j) {
      const size_t gcol = (bn & 511) + wc * 32 + j * 16 + lrow;
      #pragma unroll
      for (int reg = 0; reg < 4; ++reg) {
        const size_t grow = bm + wr * 64 + i * 16 + kblk * 4 + reg;
        float vv = acc[i][j][reg];
        if (seg < 2) {
          short hh_, ll_;
          split2(vv, hh_, ll_);
          dsth[grow * Dd + gcol] = hh_;
          dstl[grow * Dd + gcol] = ll_;
        } else {
          dsth[grow * Dd + gcol] = f2bf(vv);
        }
      }
    }
  }
}

// ------ 3-term split-bf16 NT GEMM (out-proj): C = (Ah+Al)@(Wh+Wl)^T ------
// EPI 1: f32 acc+bias -> C1.

template <int EPI>
__global__ __launch_bounds__(256) void mfma_nt3_kernel(
    const short* __restrict__ Ah, const short* __restrict__ Al,
    const short* __restrict__ Wh, const short* __restrict__ Wl,
    void* __restrict__ C1, void* __restrict__ C2,
    const float* __restrict__ bias, int Nc, int K) {
  constexpr int BM = 128, BN = 64;
  constexpr int MREP = 4, NREP = 2;
  __shared__ short Ash[BM][40], Asl[BM][40], Bsh[BN][40], Bsl[BN][40];
  const int tid = threadIdx.x;
  const int wave = tid >> 6, lane = tid & 63;
  const int wr = wave >> 1, wc = wave & 1;
  const int lrow = lane & 15, kblk = lane >> 4;
  const size_t bm = (size_t)blockIdx.y * BM, bn = (size_t)blockIdx.x * BN;
  f32x4 acc[MREP][NREP] = {};
  for (int k0 = 0; k0 < K; k0 += 32) {
    __syncthreads();
    #pragma unroll
    for (int it = 0; it < 2; ++it) {
      int id = tid + it * 256;
      int r = id >> 2, kq = id & 3;
      const size_t go = (bm + r) * K + k0 + kq * 8;
      *(short8v*)&Ash[r][kq * 8] = *(const short8v*)(Ah + go);
      *(short8v*)&Asl[r][kq * 8] = *(const short8v*)(Al + go);
    }
    {
      int r = tid >> 2, kq = tid & 3;
      const size_t go = (bn + r) * K + k0 + kq * 8;
      *(short8v*)&Bsh[r][kq * 8] = *(const short8v*)(Wh + go);
      *(short8v*)&Bsl[r][kq * 8] = *(const short8v*)(Wl + go);
    }
    __syncthreads();
    short8v afh[MREP], afl[MREP], bfh[NREP], bfl[NREP];
    #pragma unroll
    for (int i = 0; i < MREP; ++i) {
      afh[i] = *(const short8v*)&Ash[wr * 64 + i * 16 + lrow][kblk * 8];
      afl[i] = *(const short8v*)&Asl[wr * 64 + i * 16 + lrow][kblk * 8];
    }
    #pragma unroll
    for (int j = 0; j < NREP; ++j) {
      bfh[j] = *(const short8v*)&Bsh[wc * 32 + j * 16 + lrow][kblk * 8];
      bfl[j] = *(const short8v*)&Bsl[wc * 32 + j * 16 + lrow][kblk * 8];
    }
    #pragma unroll
    for (int i = 0; i < MREP; ++i)
      #pragma unroll
      for (int j = 0; j < NREP; ++j) {
        acc[i][j] = __builtin_amdgcn_mfma_f32_16x16x32_bf16(afh[i], bfh[j], acc[i][j], 0, 0, 0);
        acc[i][j] = __builtin_amdgcn_mfma_f32_16x16x32_bf16(afl[i], bfh[j], acc[i][j], 0, 0, 0);
        acc[i][j] = __builtin_amdgcn_mfma_f32_16x16x32_bf16(afh[i], bfl[j], acc[i][j], 0, 0, 0);
      }
  }
  #pragma unroll
  for (int i = 0; i < MREP; ++i) {
    #pragma unroll
    for (int j = 0; j < NREP; ++j) {
      const size_t gcol = bn + wc * 32 + j * 16 + lrow;
      float bb = 0.f;
      if constexpr (EPI == 1) bb = bias[gcol];
      #pragma unroll
      for (int reg = 0; reg < 4; ++reg) {
        const size_t grow = bm + wr * 64 + i * 16 + kblk * 4 + reg;
        float vv = acc[i][j][reg] + bb;
        if constexpr (EPI == 0) {
          short hh_, ll_;
          split2(vv, hh_, ll_);
          ((short*)C1)[grow * Nc + gcol] = hh_;
          ((short*)C2)[grow * Nc + gcol] = ll_;
        } else if constexpr (EPI == 1) {
          ((float*)C1)[grow * Nc + gcol] = vv;
        } else {
          ((short*)C1)[grow * Nc + gcol] = f2bf(vv);
        }
      }
    }
  }
}

// -------- scores: S = 8*(q k^T) + u-bias, per head, 3-term split bf16 --------
// grid (Nn/64 j-tiles, Nn/128 i-tiles, B*H). 256 threads, 2x2 waves.
// Epilogue: acc -> LDS f32 tile -> streamed float4 u-bias + store.

__global__ __launch_bounds__(256) void scores3_kernel(
    const short* __restrict__ qh, const short* __restrict__ ql,
    const short* __restrict__ kh, const short* __restrict__ kl,
    float* __restrict__ S, const float* __restrict__ u,
    const float* __restrict__ u_w, const float* __restrict__ u_b) {
  constexpr int MREP = 4, NREP = 2;
  __shared__ __align__(16) char smem[34816];  // max(staging 30720, S tile 128*68*4)
  short (*Qsh)[40] = (short(*)[40])(smem);
  short (*Qsl)[40] = (short(*)[40])(smem + 10240);
  short (*Ksh)[40] = (short(*)[40])(smem + 20480);
  short (*Ksl)[40] = (short(*)[40])(smem + 25600);
  float (*Sls)[68] = (float(*)[68])(smem);
  const int z = blockIdx.z, b = z >> 3, hh = z & 7;
  const int tid = threadIdx.x;
  const short* Qph = qh + ((size_t)b * Nn + blockIdx.y * 128) * Dd + hh * HDd;
  const short* Qpl = ql + ((size_t)b * Nn + blockIdx.y * 128) * Dd + hh * HDd;
  const short* Kph = kh + ((size_t)b * Nn + blockIdx.x * 64) * Dd + hh * HDd;
  const short* Kpl = kl + ((size_t)b * Nn + blockIdx.x * 64) * Dd + hh * HDd;
  const int wave = tid >> 6, lane = tid & 63;
  const int wr = wave >> 1, wc = wave & 1;
  const int lrow = lane & 15, kblk = lane >> 4;
  f32x4 acc[MREP][NREP] = {};
  #pragma unroll
  for (int k0 = 0; k0 < HDd; k0 += 32) {
    __syncthreads();
    #pragma unroll
    for (int it = 0; it < 2; ++it) {
      int id = tid + it * 256;
      int r = id >> 2, kq = id & 3;
      const size_t go = (size_t)r * Dd + k0 + kq * 8;
      *(short8v*)&Qsh[r][kq * 8] = *(const short8v*)(Qph + go);
      *(short8v*)&Qsl[r][kq * 8] = *(const short8v*)(Qpl + go);
    }
    {
      int r = tid >> 2, kq = tid & 3;
      const size_t go = (size_t)r * Dd + k0 + kq * 8;
      *(short8v*)&Ksh[r][kq * 8] = *(const short8v*)(Kph + go);
      *(short8v*)&Ksl[r][kq * 8] = *(const short8v*)(Kpl + go);
    }
    __syncthreads();
    short8v afh[MREP], afl[MREP], bfh[NREP], bfl[NREP];
    #pragma unroll
    for (int i = 0; i < MREP; ++i) {
      afh[i] = *(const short8v*)&Qsh[wr * 64 + i * 16 + lrow][kblk * 8];
      afl[i] = *(const short8v*)&Qsl[wr * 64 + i * 16 + lrow][kblk * 8];
    }
    #pragma unroll
    for (int j = 0; j < NREP; ++j) {
      bfh[j] = *(const short8v*)&Ksh[wc * 32 + j * 16 + lrow][kblk * 8];
      bfl[j] = *(const short8v*)&Ksl[wc * 32 + j * 16 + lrow][kblk * 8];
    }
    #pragma unroll
    for (int i = 0; i < MREP; ++i)
      #pragma unroll
      for (int j = 0; j < NREP; ++j) {
        acc[i][j] = __builtin_amdgcn_mfma_f32_16x16x32_bf16(afh[i], bfh[j], acc[i][j], 0, 0, 0);
        acc[i][j] = __builtin_amdgcn_mfma_f32_16x16x32_bf16(afl[i], bfh[j], acc[i][j], 0, 0, 0);
        acc[i][j] = __builtin_amdgcn_mfma_f32_16x16x32_bf16(afh[i], bfl[j], acc[i][j], 0, 0, 0);
      }
  }
  __syncthreads();  // all MFMA LDS reads done before overwriting staging with S tile
  #pragma unroll
  for (int i = 0; i < MREP; ++i)
    #pragma unroll
    for (int j = 0; j < NREP; ++j)
      #pragma unroll
      for (int reg = 0; reg < 4; ++reg)
        Sls[wr * 64 + i * 16 + kblk * 4 + reg][wc * 32 + j * 16 + lrow] =
            8.f * acc[i][j][reg];
  __syncthreads();
  // ---- streamed epilogue: float4 u loads, float4 store ----
  const float* ub_ = u + (size_t)b * UEe * Nn * Nn;
  float uw[UEe];
  #pragma unroll
  for (int c = 0; c < UEe; ++c) uw[c] = u_w[hh * UEe + c];
  const float ub = u_b[hh];
  float* Sp = S + (size_t)z * Nn * Nn;
  const int trow = tid >> 4;
  const int tcol = (tid & 15) * 4;
  #pragma unroll
  for (int p = 0; p < 8; ++p) {
    const int row = p * 16 + trow;
    const size_t goff = (size_t)(blockIdx.y * 128 + row) * Nn + blockIdx.x * 64 + tcol;
    float4 v = *(const float4*)&Sls[row][tcol];
    v.x += ub; v.y += ub; v.z += ub; v.w += ub;
    #pragma unroll
    for (int c = 0; c < UEe; ++c) {
      float4 uv = *(const float4*)(ub_ + (size_t)c * Nn * Nn + goff);
      v.x = fmaf(uw[c], uv.x, v.x); v.y = fmaf(uw[c], uv.y, v.y);
      v.z = fmaf(uw[c], uv.z, v.z); v.w = fmaf(uw[c], uv.w, v.w);
    }
    *(float4*)(Sp + goff) = v;
  }
}

// -------- fused softmax + P write + P@V -> ctx (split bf16 out) --------
// grid (16 row-tiles of 32, 128 z). 256 threads. In-place S->P in attnW.

__global__ __launch_bounds__(256) void smctx_kernel(
    float* __restrict__ P, const short* __restrict__ vT,
    short* __restrict__ ctxh, short* __restrict__ ctxl) {
  __shared__ short Ps[32][520];
  __shared__ short Bs[64][136];
  const int z = blockIdx.y, b = z >> 3, hh = z & 7;
  const int row0 = blockIdx.x * 32;
  const int tid = threadIdx.x;
  const int lr = tid >> 3, sub = tid & 7;
  float* Sp = P + (size_t)z * Nn * Nn + (size_t)(row0 + lr) * Nn + sub * 64;
  float4 s[16];
  #pragma unroll
  for (int q = 0; q < 16; ++q) s[q] = *(const float4*)(Sp + q * 4);
  float m = -1e30f;
  #pragma unroll
  for (int q = 0; q < 16; ++q)
    m = fmaxf(m, fmaxf(fmaxf(s[q].x, s[q].y), fmaxf(s[q].z, s[q].w)));
  m = fmaxf(m, __shfl_xor(m, 1));
  m = fmaxf(m, __shfl_xor(m, 2));
  m = fmaxf(m, __shfl_xor(m, 4));
  float sum = 0.f;
  #pragma unroll
  for (int q = 0; q < 16; ++q) {
    s[q].x = __expf(s[q].x - m); s[q].y = __expf(s[q].y - m);
    s[q].z = __expf(s[q].z - m); s[q].w = __expf(s[q].w - m);
    sum += (s[q].x + s[q].y) + (s[q].z + s[q].w);
  }
  sum += __shfl_xor(sum, 1);
  sum += __shfl_xor(sum, 2);
  sum += __shfl_xor(sum, 4);
  const float rr = 1.f / sum;
  #pragma unroll
  for (int q = 0; q < 16; ++q) {
    s[q].x *= rr; s[q].y *= rr; s[q].z *= rr; s[q].w *= rr;
    *(float4*)(Sp + q * 4) = s[q];
  }
  #pragma unroll
  for (int q = 0; q < 8; ++q) {
    float4 a = s[2 * q], c = s[2 * q + 1];
    short8v pk;
    pk[0] = f2bf(a.x); pk[1] = f2bf(a.y); pk[2] = f2bf(a.z); pk[3] = f2bf(a.w);
    pk[4] = f2bf(c.x); pk[5] = f2bf(c.y); pk[6] = f2bf(c.z); pk[7] = f2bf(c.w);
    *(short8v*)&Ps[lr][sub * 64 + q * 8] = pk;
  }
  // ---- PV MFMA: ctx_tile[32][64] = P_tile[32][512] @ V[512][64] ----
  const int wave = tid >> 6, lane = tid & 63;
  const int wr = wave >> 1, wc = wave & 1;
  const int lrow = lane & 15, kblk = lane >> 4;
  f32x4 acc0 = {}, acc1 = {};
  for (int kc = 0; kc < 4; ++kc) {
    __syncthreads();
    #pragma unroll
    for (int it = 0; it < 4; ++it) {
      int id = tid + it * 256;
      int rrow = id >> 4, k8 = id & 15;
      *(short8v*)&Bs[rrow][k8 * 8] =
          *(const short8v*)(vT + ((size_t)z * HDd + rrow) * Nn + kc * 128 + k8 * 8);
    }
    __syncthreads();
    #pragma unroll
    for (int ks = 0; ks < 4; ++ks) {
      short8v af = *(const short8v*)&Ps[wr * 16 + lrow][kc * 128 + ks * 32 + kblk * 8];
      short8v b0 = *(const short8v*)&Bs[wc * 32 + lrow][ks * 32 + kblk * 8];
      short8v b1 = *(const short8v*)&Bs[wc * 32 + 16 + lrow][ks * 32 + kblk * 8];
      acc0 = __builtin_amdgcn_mfma_f32_16x16x32_bf16(af, b0, acc0, 0, 0, 0);
      acc1 = __builtin_amdgcn_mfma_f32_16x16x32_bf16(af, b1, acc1, 0, 0, 0);
    }
  }
  const size_t outbase =
      ((size_t)(b * Nn + row0 + wr * 16 + kblk * 4)) * Dd + hh * HDd + wc * 32 + lrow;
  #pragma unroll
  for (int reg = 0; reg < 4; ++reg) {
    short h0, l0, h1, l1;
    split2(acc0[reg], h0, l0);
    split2(acc1[reg], h1, l1);
    ctxh[outbase + (size_t)reg * Dd] = h0;
    ctxl[outbase + (size_t)reg * Dd] = l0;
    ctxh[outbase + (size_t)reg * Dd + 16] = h1;
    ctxl[outbase + (size_t)reg * Dd + 16] = l1;
  }
}

// ---------------- bf16 MFMA NT GEMM (FFN): C[M,Nc] = A[M,K] @ W[Nc,K]^T ----------------
// EPI 0: silu(acc+bias)->bf16. 1: acc+bias+res->f32.

template <int BM, int BN, int EPI>
__global__ __launch_bounds__(256) void mfma_nt_kernel(
    const short* __restrict__ Ag, const short* __restrict__ Wg,
    void* __restrict__ Cv, const float* __restrict__ bias,
    const float* __restrict__ res, int Nc, int K) {
  constexpr int MREP = BM / 32, NREP = BN / 32;
  __shared__ short As[BM][72];
  __shared__ short Bs[BN][72];
  const int tid = threadIdx.x;
  const int wave = tid >> 6, lane = tid & 63;
  const int wr = wave >> 1, wc = wave & 1;
  const int lrow = lane & 15, kblk = lane >> 4;
  const size_t bm = (size_t)blockIdx.y * BM, bn = (size_t)blockIdx.x * BN;
  f32x4 acc[MREP][NREP] = {};
  for (int k0 = 0; k0 < K; k0 += 32) {
    __syncthreads();
    #pragma unroll
    for (int it = 0; it < BM / 64; ++it) {
      int id = tid + it * 256;
      int r = id >> 2, kq = id & 3;
      *(short8v*)&As[r][kq * 8] = *(const short8v*)(Ag + (bm + r) * K + k0 + kq * 8);
    }
    #pragma unroll
    for (int it = 0; it < BN / 64; ++it) {
      int id = tid + it * 256;
      int r = id >> 2, kq = id & 3;
      *(short8v*)&Bs[r][kq * 8] = *(const short8v*)(Wg + (bn + r) * K + k0 + kq * 8);
    }
    __syncthreads();
    short8v af[MREP], bf[NREP];
    #pragma unroll
    for (int i = 0; i < MREP; ++i)
      af[i] = *(const short8v*)&As[wr * (BM / 2) + i * 16 + lrow][kblk * 8];
    #pragma unroll
    for (int j = 0; j < NREP; ++j)
      bf[j] = *(const short8v*)&Bs[wc * (BN / 2) + j * 16 + lrow][kblk * 8];
    #pragma unroll
    for (int i = 0; i < MREP; ++i)
      #pragma unroll
      for (int j = 0; j < NREP; ++j)
        acc[i][j] = __builtin_amdgcn_mfma_f32_16x16x32_bf16(af[i], bf[j], acc[i][j], 0, 0, 0);
  }
  #pragma unroll
  for (int i = 0; i < MREP; ++i) {
    #pragma unroll
    for (int j = 0; j < NREP; ++j) {
      const size_t gcol = bn + wc * (BN / 2) + j * 16 + lrow;
      const float bb = bias[gcol];
      #pragma unroll
      for (int reg = 0; reg < 4; ++reg) {
        const size_t grow = bm + wr * (BM / 2) + i * 16 + kblk * 4 + reg;
        float vv = acc[i][j][reg] + bb;
        if constexpr (EPI == 0) {
          vv = vv / (1.f + __expf(-vv));
          ((short*)Cv)[grow * Nc + gcol] = f2bf(vv);
        } else {
          ((float*)Cv)[grow * Nc + gcol] = vv + res[grow * Nc + gcol];
        }
      }
    }
  }
}

// ---------------- host launch ----------------

extern "C" void kernel_launch(void* const* d_in, const int* in_sizes, int n_in,
                              void* d_out, int out_size, void* d_ws, size_t ws_size,
                              hipStream_t stream) {
  const float* x     = (const float*)d_in[0];
  const float* u     = (const float*)d_in[1];
  const float* ln1_w = (const float*)d_in[2];
  const float* ln1_b = (const float*)d_in[3];
  const float* ln2_w = (const float*)d_in[4];
  const float* ln2_b = (const float*)d_in[5];
  const float* wq    = (const float*)d_in[6];
  const float* wk    = (const float*)d_in[7];
  const float* wv    = (const float*)d_in[8];
  const float* wo    = (const float*)d_in[9];
  const float* bo    = (const float*)d_in[10];
  const float* u_w   = (const float*)d_in[11];
  const float* u_b   = (const float*)d_in[12];
  const float* rms_w = (const float*)d_in[13];
  const float* w1    = (const float*)d_in[14];
  const float* b1    = (const float*)d_in[15];
  const float* w2    = (const float*)d_in[16];
  const float* b2    = (const float*)d_in[17];

  float* out   = (float*)d_out;
  float* attnW = out + (size_t)Bb * Nn * Dd;  // second output: [B,H,N,N]

  const size_t SB = (size_t)Bb * Nn * Dd * 2;  // 8 MB (one bf16 activation buffer)
  char* wsb = (char*)d_ws;
  // slot map (8 MB each):
  // 0: xnh -> vTh -> zbf | 1: xnl -> ctxh -> h1bf | 2: qh -> aout[0:8MB]
  // 3: ql -> aout[8:16MB] | 4: kh -> hbuf[0:8MB] | 5: kl -> hbuf[8:16MB]
  // 6: vh -> ctxl
  short* xnh  = (short*)(wsb + 0 * SB);
  short* xnl  = (short*)(wsb + 1 * SB);
  short* qh   = (short*)(wsb + 2 * SB);
  short* ql   = (short*)(wsb + 3 * SB);
  short* kh   = (short*)(wsb + 4 * SB);
  short* kl   = (short*)(wsb + 5 * SB);
  short* vh   = (short*)(wsb + 6 * SB);
  short* vTh  = (short*)(wsb + 0 * SB);
  short* ctxh = (short*)(wsb + 1 * SB);
  short* ctxl = (short*)(wsb + 6 * SB);
  float* aout = (float*)(wsb + 2 * SB);
  float* hbuf = (float*)(wsb + 4 * SB);
  short* zbf  = (short*)(wsb + 0 * SB);
  short* h1bf = (short*)(wsb + 1 * SB);
  const size_t WTBYTES = 8 * (size_t)Dd * Dd * 2 + 2 * (size_t)DFFf * Dd * 2;  // 8 MB
  const size_t wt = (ws_size - WTBYTES) & ~(size_t)255;
  // concatenated QKV weights: hi [1536][512], lo [1536][512]
  short* wAh = (short*)(wsb + wt);
  short* wAl = wAh + 3 * (size_t)Dd * Dd;
  short* woh = wAl + 3 * (size_t)Dd * Dd;
  short* wol = woh + (size_t)Dd * Dd;
  short* w1h = wol + (size_t)Dd * Dd;
  short* w2h = w1h + (size_t)DFFf * Dd;

  const int MR = Bb * Nn;  // 8192 rows

  // 0. weight converts
  cvt2_kernel<<<256, 256, 0, stream>>>(wq, wAh, wAl, Dd * Dd / 4);
  cvt2_kernel<<<256, 256, 0, stream>>>(wk, wAh + (size_t)Dd * Dd, wAl + (size_t)Dd * Dd, Dd * Dd / 4);
  cvt2_kernel<<<256, 256, 0, stream>>>(wv, wAh + 2 * (size_t)Dd * Dd, wAl + 2 * (size_t)Dd * Dd, Dd * Dd / 4);
  cvt2_kernel<<<256, 256, 0, stream>>>(wo, woh, wol, Dd * Dd / 4);
  cvt_kernel<<<1024, 256, 0, stream>>>(w1, w1h, DFFf * Dd / 4);
  cvt_kernel<<<1024, 256, 0, stream>>>(w2, w2h, DFFf * Dd / 4);

  // 1. LayerNorm1 -> split bf16
  ln1_kernel<<<MR, 256, 0, stream>>>(x, ln1_w, ln1_b, xnh, xnl);

  // 2. merged Q,K,V projection (3-term split MFMA)
  dim3 gQKV(3 * Dd / 64, MR / 128);
  mfma_qkv3_kernel<<<gQKV,256,0,stream>>>(xnh, xnl, wAh, wAl, qh, ql, kh, kl, vh);

  // 3. V transpose per head
  dim3 gVt(Nn / 64, Bb * Hh);
  vt_kernel<<<gVt, 256, 0, stream>>>(vh, vTh);

  // 4. scores = 8 q k^T + u-bias -> attnW (raw S, f32), 3-term + streamed epilogue
  dim3 gSc(Nn / 64, Nn / 128, Bb * Hh);
  scores3_kernel<<<gSc, 256, 0, stream>>>(qh, ql, kh, kl, attnW, u, u_w, u_b);

  // 5. fused softmax (in-place P) + P@V -> ctx split bf16
  dim3 gSm(Nn / 32, Bb * Hh);
  smctx_kernel<<<gSm, 256, 0, stream>>>(attnW, vTh, ctxh, ctxl);

  // 6. attn_out = ctx @ wo^T + bo (3-term, f32 out)
  dim3 gProj(Dd / 64, MR / 128);
  mfma_nt3_kernel<1><<<gProj,256,0,stream>>>(ctxh, ctxl, woh, wol, aout, nullptr, bo, Dd, Dd);

  // 7. h = LN2(attn_out) + x ; zbf = bf16(RMSNorm(h))
  hz_kernel<<<MR, 256, 0, stream>>>(aout, x, ln2_w, ln2_b, rms_w, hbuf, zbf);

  // 8/9. FFN bf16 MFMA, 4 chunks of 2048 rows (h1bf = one 8MB slot)
  const int rows = 2048;
  for (int m0 = 0; m0 < MR; m0 += rows) {
    dim3 gF1(DFFf / 128, rows / 128);
    mfma_nt_kernel<128,128,0><<<gF1,256,0,stream>>>(
        zbf + (size_t)m0 * Dd, w1h, h1bf, b1, nullptr, DFFf, Dd);
    dim3 gF2(Dd / 128, rows / 64);
    mfma_nt_kernel<64,128,1><<<gF2,256,0,stream>>>(
        h1bf, w2h, out + (size_t)m0 * Dd, b2, hbuf + (size_t)m0 * Dd, Dd, DFFf);
  }
}

// Round 9
// 348.820 us; speedup vs baseline: 2.9470x; 1.5934x over previous
//
#include <hip/hip_runtime.h>
#include <math.h>

static constexpr int Bb  = 16;
static constexpr int Nn  = 512;
static constexpr int Dd  = 512;
static constexpr int Hh  = 8;
static constexpr int HDd = 64;
static constexpr int UEe = 6;
static constexpr int DFFf= 2048;

typedef __attribute__((ext_vector_type(8))) short short8v;
typedef __attribute__((ext_vector_type(4))) float f32x4;

__device__ __forceinline__ short f2bf(float f) {
  unsigned u = __float_as_uint(f);
  unsigned r = (u + 0x7fffu + ((u >> 16) & 1u)) >> 16;
  return (short)r;
}
__device__ __forceinline__ float bf2f(short h) {
  return __uint_as_float(((unsigned)(unsigned short)h) << 16);
}
__device__ __forceinline__ void split2(float v, short& hi, short& lo) {
  hi = f2bf(v);
  lo = f2bf(v - bf2f(hi));
}

// ---------------- block reduction helpers (256 threads, 4 waves) ----------------

__device__ __forceinline__ float2 block_sum2(float a, float b, float* sb) {
  #pragma unroll
  for (int o = 32; o; o >>= 1) { a += __shfl_down(a, o); b += __shfl_down(b, o); }
  const int lane = threadIdx.x & 63, wid = threadIdx.x >> 6;
  if (lane == 0) { sb[wid] = a; sb[4 + wid] = b; }
  __syncthreads();
  float ra = sb[0] + sb[1] + sb[2] + sb[3];
  float rb = sb[4] + sb[5] + sb[6] + sb[7];
  __syncthreads();
  return make_float2(ra, rb);
}

__device__ __forceinline__ float block_sum1(float a, float* sb) {
  #pragma unroll
  for (int o = 32; o; o >>= 1) a += __shfl_down(a, o);
  const int lane = threadIdx.x & 63, wid = threadIdx.x >> 6;
  if (lane == 0) sb[wid] = a;
  __syncthreads();
  float ra = sb[0] + sb[1] + sb[2] + sb[3];
  __syncthreads();
  return ra;
}

// ---------------- LayerNorm on x -> xn (split bf16 hi/lo) ----------------

__global__ __launch_bounds__(256) void ln1_kernel(
    const float* __restrict__ x, const float* __restrict__ w,
    const float* __restrict__ b, short* __restrict__ oh, short* __restrict__ ol) {
  __shared__ float sb[8];
  const size_t row = blockIdx.x;
  const int t = threadIdx.x;
  const float* xr = x + row * Dd;
  float2 xv = *(const float2*)(xr + 2 * t);
  float2 r = block_sum2(xv.x + xv.y, xv.x * xv.x + xv.y * xv.y, sb);
  const float mu = r.x * (1.f / Dd);
  const float var = r.y * (1.f / Dd) - mu * mu;
  const float rstd = rsqrtf(var + 1e-5f);
  float2 wv = *(const float2*)(w + 2 * t);
  float2 bv = *(const float2*)(b + 2 * t);
  float v0 = (xv.x - mu) * rstd * wv.x + bv.x;
  float v1 = (xv.y - mu) * rstd * wv.y + bv.y;
  short2 h2, l2;
  split2(v0, h2.x, l2.x);
  split2(v1, h2.y, l2.y);
  *(short2*)(oh + row * Dd + 2 * t) = h2;
  *(short2*)(ol + row * Dd + 2 * t) = l2;
}

// ------- LN2(attn_out)+residual -> h (f32) ; RMSNorm(h) -> zbf (bf16) -------

__global__ __launch_bounds__(256) void hz_kernel(
    const float* __restrict__ ao, const float* __restrict__ xres,
    const float* __restrict__ w, const float* __restrict__ b,
    const float* __restrict__ rw,
    float* __restrict__ h, short* __restrict__ zbf) {
  __shared__ float sb[8];
  const size_t row = blockIdx.x;
  const int t = threadIdx.x;
  float2 av = *(const float2*)(ao + row * Dd + 2 * t);
  float2 r = block_sum2(av.x + av.y, av.x * av.x + av.y * av.y, sb);
  const float mu = r.x * (1.f / Dd);
  const float var = r.y * (1.f / Dd) - mu * mu;
  const float rstd = rsqrtf(var + 1e-5f);
  float2 wv = *(const float2*)(w + 2 * t);
  float2 bv = *(const float2*)(b + 2 * t);
  float2 xv = *(const float2*)(xres + row * Dd + 2 * t);
  float2 hv;
  hv.x = (av.x - mu) * rstd * wv.x + bv.x + xv.x;
  hv.y = (av.y - mu) * rstd * wv.y + bv.y + xv.y;
  *(float2*)(h + row * Dd + 2 * t) = hv;
  float ms = block_sum1(hv.x * hv.x + hv.y * hv.y, sb) * (1.f / Dd);
  const float rr = rsqrtf(ms + 1.1920929e-07f);
  float2 rwv = *(const float2*)(rw + 2 * t);
  short2 zv;
  zv.x = f2bf(hv.x * rr * rwv.x);
  zv.y = f2bf(hv.y * rr * rwv.y);
  *(short2*)(zbf + row * Dd + 2 * t) = zv;
}

// ---------------- f32 -> bf16 converts ----------------

__global__ __launch_bounds__(256) void cvt_kernel(
    const float* __restrict__ in, short* __restrict__ out, int n4) {
  int i = blockIdx.x * 256 + threadIdx.x;
  if (i < n4) {
    float4 v = ((const float4*)in)[i];
    short4 o;
    o.x = f2bf(v.x); o.y = f2bf(v.y); o.z = f2bf(v.z); o.w = f2bf(v.w);
    ((short4*)out)[i] = o;
  }
}

__global__ __launch_bounds__(256) void cvt2_kernel(
    const float* __restrict__ in, short* __restrict__ hi,
    short* __restrict__ lo, int n4) {
  int i = blockIdx.x * 256 + threadIdx.x;
  if (i < n4) {
    float4 v = ((const float4*)in)[i];
    short4 h, l;
    split2(v.x, h.x, l.x); split2(v.y, h.y, l.y);
    split2(v.z, h.z, l.z); split2(v.w, h.w, l.w);
    ((short4*)hi)[i] = h;
    ((short4*)lo)[i] = l;
  }
}

// -------- V transpose: v[8192][512] bf16 -> vT[b][h][hd(64)][n(512)] bf16 --------

__global__ __launch_bounds__(256) void vt_kernel(
    const short* __restrict__ v, short* __restrict__ vT) {
  __shared__ short Lt[64][72];
  const int z = blockIdx.y, b = z >> 3, hh = z & 7;
  const int n0 = blockIdx.x * 64;
  const int tid = threadIdx.x;
  #pragma unroll
  for (int it = 0; it < 2; ++it) {
    int id = tid + it * 256;
    int r = id >> 3, c8 = id & 7;
    *(short8v*)&Lt[r][c8 * 8] =
        *(const short8v*)(v + ((size_t)(b * Nn + n0 + r)) * Dd + hh * HDd + c8 * 8);
  }
  __syncthreads();
  #pragma unroll
  for (int it = 0; it < 2; ++it) {
    int id = tid + it * 256;
    int c = id >> 3, r8 = id & 7;
    short8v g;
    #pragma unroll
    for (int k = 0; k < 8; ++k) g[k] = Lt[r8 * 8 + k][c];
    *(short8v*)(vT + ((size_t)z * HDd + c) * Nn + n0 + r8 * 8) = g;
  }
}

// ------ merged QKV 3-term split-bf16 NT GEMM ------

__global__ __launch_bounds__(256) void mfma_qkv3_kernel(
    const short* __restrict__ Ah, const short* __restrict__ Al,
    const short* __restrict__ Wh, const short* __restrict__ Wl,
    short* __restrict__ qh_, short* __restrict__ ql_,
    short* __restrict__ kh_, short* __restrict__ kl_,
    short* __restrict__ vh_) {
  constexpr int MREP = 4, NREP = 2;
  __shared__ short Ash[128][40], Asl[128][40], Bsh[64][40], Bsl[64][40];
  const int tid = threadIdx.x;
  const int wave = tid >> 6, lane = tid & 63;
  const int wr = wave >> 1, wc = wave & 1;
  const int lrow = lane & 15, kblk = lane >> 4;
  const size_t bm = (size_t)blockIdx.y * 128, bn = (size_t)blockIdx.x * 64;
  f32x4 acc[MREP][NREP] = {};
  for (int k0 = 0; k0 < Dd; k0 += 32) {
    __syncthreads();
    #pragma unroll
    for (int it = 0; it < 2; ++it) {
      int id = tid + it * 256;
      int r = id >> 2, kq = id & 3;
      const size_t go = (bm + r) * Dd + k0 + kq * 8;
      *(short8v*)&Ash[r][kq * 8] = *(const short8v*)(Ah + go);
      *(short8v*)&Asl[r][kq * 8] = *(const short8v*)(Al + go);
    }
    {
      int r = tid >> 2, kq = tid & 3;
      const size_t go = (bn + r) * Dd + k0 + kq * 8;
      *(short8v*)&Bsh[r][kq * 8] = *(const short8v*)(Wh + go);
      *(short8v*)&Bsl[r][kq * 8] = *(const short8v*)(Wl + go);
    }
    __syncthreads();
    short8v afh[MREP], afl[MREP], bfh[NREP], bfl[NREP];
    #pragma unroll
    for (int i = 0; i < MREP; ++i) {
      afh[i] = *(const short8v*)&Ash[wr * 64 + i * 16 + lrow][kblk * 8];
      afl[i] = *(const short8v*)&Asl[wr * 64 + i * 16 + lrow][kblk * 8];
    }
    #pragma unroll
    for (int j = 0; j < NREP; ++j) {
      bfh[j] = *(const short8v*)&Bsh[wc * 32 + j * 16 + lrow][kblk * 8];
      bfl[j] = *(const short8v*)&Bsl[wc * 32 + j * 16 + lrow][kblk * 8];
    }
    #pragma unroll
    for (int i = 0; i < MREP; ++i)
      #pragma unroll
      for (int j = 0; j < NREP; ++j) {
        acc[i][j] = __builtin_amdgcn_mfma_f32_16x16x32_bf16(afh[i], bfh[j], acc[i][j], 0, 0, 0);
        acc[i][j] = __builtin_amdgcn_mfma_f32_16x16x32_bf16(afl[i], bfh[j], acc[i][j], 0, 0, 0);
        acc[i][j] = __builtin_amdgcn_mfma_f32_16x16x32_bf16(afh[i], bfl[j], acc[i][j], 0, 0, 0);
      }
  }
  const int seg = (int)(bn >> 9);  // uniform per block
  short* dsth = seg == 0 ? qh_ : (seg == 1 ? kh_ : vh_);
  short* dstl = seg == 0 ? ql_ : kl_;
  #pragma unroll
  for (int i = 0; i < MREP; ++i) {
    #pragma unroll
    for (int j = 0; j < NREP; ++j) {
      const size_t gcol = (bn & 511) + wc * 32 + j * 16 + lrow;
      #pragma unroll
      for (int reg = 0; reg < 4; ++reg) {
        const size_t grow = bm + wr * 64 + i * 16 + kblk * 4 + reg;
        float vv = acc[i][j][reg];
        if (seg < 2) {
          short hh_, ll_;
          split2(vv, hh_, ll_);
          dsth[grow * Dd + gcol] = hh_;
          dstl[grow * Dd + gcol] = ll_;
        } else {
          dsth[grow * Dd + gcol] = f2bf(vv);
        }
      }
    }
  }
}

// ------ 3-term split-bf16 NT GEMM (out-proj): C = (Ah+Al)@(Wh+Wl)^T ------

template <int EPI>
__global__ __launch_bounds__(256) void mfma_nt3_kernel(
    const short* __restrict__ Ah, const short* __restrict__ Al,
    const short* __restrict__ Wh, const short* __restrict__ Wl,
    void* __restrict__ C1, void* __restrict__ C2,
    const float* __restrict__ bias, int Nc, int K) {
  constexpr int BM = 128, BN = 64;
  constexpr int MREP = 4, NREP = 2;
  __shared__ short Ash[BM][40], Asl[BM][40], Bsh[BN][40], Bsl[BN][40];
  const int tid = threadIdx.x;
  const int wave = tid >> 6, lane = tid & 63;
  const int wr = wave >> 1, wc = wave & 1;
  const int lrow = lane & 15, kblk = lane >> 4;
  const size_t bm = (size_t)blockIdx.y * BM, bn = (size_t)blockIdx.x * BN;
  f32x4 acc[MREP][NREP] = {};
  for (int k0 = 0; k0 < K; k0 += 32) {
    __syncthreads();
    #pragma unroll
    for (int it = 0; it < 2; ++it) {
      int id = tid + it * 256;
      int r = id >> 2, kq = id & 3;
      const size_t go = (bm + r) * K + k0 + kq * 8;
      *(short8v*)&Ash[r][kq * 8] = *(const short8v*)(Ah + go);
      *(short8v*)&Asl[r][kq * 8] = *(const short8v*)(Al + go);
    }
    {
      int r = tid >> 2, kq = tid & 3;
      const size_t go = (bn + r) * K + k0 + kq * 8;
      *(short8v*)&Bsh[r][kq * 8] = *(const short8v*)(Wh + go);
      *(short8v*)&Bsl[r][kq * 8] = *(const short8v*)(Wl + go);
    }
    __syncthreads();
    short8v afh[MREP], afl[MREP], bfh[NREP], bfl[NREP];
    #pragma unroll
    for (int i = 0; i < MREP; ++i) {
      afh[i] = *(const short8v*)&Ash[wr * 64 + i * 16 + lrow][kblk * 8];
      afl[i] = *(const short8v*)&Asl[wr * 64 + i * 16 + lrow][kblk * 8];
    }
    #pragma unroll
    for (int j = 0; j < NREP; ++j) {
      bfh[j] = *(const short8v*)&Bsh[wc * 32 + j * 16 + lrow][kblk * 8];
      bfl[j] = *(const short8v*)&Bsl[wc * 32 + j * 16 + lrow][kblk * 8];
    }
    #pragma unroll
    for (int i = 0; i < MREP; ++i)
      #pragma unroll
      for (int j = 0; j < NREP; ++j) {
        acc[i][j] = __builtin_amdgcn_mfma_f32_16x16x32_bf16(afh[i], bfh[j], acc[i][j], 0, 0, 0);
        acc[i][j] = __builtin_amdgcn_mfma_f32_16x16x32_bf16(afl[i], bfh[j], acc[i][j], 0, 0, 0);
        acc[i][j] = __builtin_amdgcn_mfma_f32_16x16x32_bf16(afh[i], bfl[j], acc[i][j], 0, 0, 0);
      }
  }
  #pragma unroll
  for (int i = 0; i < MREP; ++i) {
    #pragma unroll
    for (int j = 0; j < NREP; ++j) {
      const size_t gcol = bn + wc * 32 + j * 16 + lrow;
      float bb = 0.f;
      if constexpr (EPI == 1) bb = bias[gcol];
      #pragma unroll
      for (int reg = 0; reg < 4; ++reg) {
        const size_t grow = bm + wr * 64 + i * 16 + kblk * 4 + reg;
        float vv = acc[i][j][reg] + bb;
        if constexpr (EPI == 0) {
          short hh_, ll_;
          split2(vv, hh_, ll_);
          ((short*)C1)[grow * Nc + gcol] = hh_;
          ((short*)C2)[grow * Nc + gcol] = ll_;
        } else if constexpr (EPI == 1) {
          ((float*)C1)[grow * Nc + gcol] = vv;
        } else {
          ((short*)C1)[grow * Nc + gcol] = f2bf(vv);
        }
      }
    }
  }
}

// -------- scores8: all heads per block, u in registers --------
// grid (8 j-tiles, 8 i-tiles, 16 b). 256 threads, 2x2 waves, 64x64 tile/head.
// u tile (6 planes x 64x64) preloaded to registers once; heads looped.
// Staging arrays hold the FULL K=64: [64][72] (64 cols + 8 pad).

__global__ __launch_bounds__(256) void scores8_kernel(
    const short* __restrict__ qh, const short* __restrict__ ql,
    const short* __restrict__ kh, const short* __restrict__ kl,
    float* __restrict__ S, const float* __restrict__ u,
    const float* __restrict__ u_w, const float* __restrict__ u_b) {
  __shared__ short Qsh[64][72], Qsl[64][72], Ksh[64][72], Ksl[64][72];
  __shared__ float Sls[64][68];
  const int b = blockIdx.z;
  const int i0 = blockIdx.y * 64, j0 = blockIdx.x * 64;
  const int tid = threadIdx.x;
  const int wave = tid >> 6, lane = tid & 63;
  const int wr = wave >> 1, wc = wave & 1;
  const int lrow = lane & 15, kblk = lane >> 4;
  const int trow = tid >> 4;          // 0..15
  const int tcol = (tid & 15) * 4;    // 0,4,..,60
  // ---- preload u tile into registers (fully unrolled -> stays in VGPRs) ----
  const float* ub_ = u + (size_t)b * UEe * Nn * Nn;
  float4 ureg[UEe][4];
  #pragma unroll
  for (int c = 0; c < UEe; ++c)
    #pragma unroll
    for (int p = 0; p < 4; ++p)
      ureg[c][p] = *(const float4*)(ub_ + (size_t)c * Nn * Nn +
                                    (size_t)(i0 + p * 16 + trow) * Nn + j0 + tcol);

  for (int h = 0; h < Hh; ++h) {
    __syncthreads();  // prev head's LDS reads (MFMA + epilogue Sls) all done
    #pragma unroll
    for (int it = 0; it < 2; ++it) {
      int id = tid + it * 256;
      int r = id >> 3, kq = id & 7;
      const size_t gq = ((size_t)(b * Nn) + i0 + r) * Dd + h * HDd + kq * 8;
      const size_t gk = ((size_t)(b * Nn) + j0 + r) * Dd + h * HDd + kq * 8;
      *(short8v*)&Qsh[r][kq * 8] = *(const short8v*)(qh + gq);
      *(short8v*)&Qsl[r][kq * 8] = *(const short8v*)(ql + gq);
      *(short8v*)&Ksh[r][kq * 8] = *(const short8v*)(kh + gk);
      *(short8v*)&Ksl[r][kq * 8] = *(const short8v*)(kl + gk);
    }
    __syncthreads();
    f32x4 acc[2][2] = {};
    #pragma unroll
    for (int ks = 0; ks < 2; ++ks) {
      short8v afh[2], afl[2], bfh[2], bfl[2];
      #pragma unroll
      for (int i = 0; i < 2; ++i) {
        afh[i] = *(const short8v*)&Qsh[wr * 32 + i * 16 + lrow][ks * 32 + kblk * 8];
        afl[i] = *(const short8v*)&Qsl[wr * 32 + i * 16 + lrow][ks * 32 + kblk * 8];
      }
      #pragma unroll
      for (int j = 0; j < 2; ++j) {
        bfh[j] = *(const short8v*)&Ksh[wc * 32 + j * 16 + lrow][ks * 32 + kblk * 8];
        bfl[j] = *(const short8v*)&Ksl[wc * 32 + j * 16 + lrow][ks * 32 + kblk * 8];
      }
      #pragma unroll
      for (int i = 0; i < 2; ++i)
        #pragma unroll
        for (int j = 0; j < 2; ++j) {
          acc[i][j] = __builtin_amdgcn_mfma_f32_16x16x32_bf16(afh[i], bfh[j], acc[i][j], 0, 0, 0);
          acc[i][j] = __builtin_amdgcn_mfma_f32_16x16x32_bf16(afl[i], bfh[j], acc[i][j], 0, 0, 0);
          acc[i][j] = __builtin_amdgcn_mfma_f32_16x16x32_bf16(afh[i], bfl[j], acc[i][j], 0, 0, 0);
        }
    }
    // dump acc -> LDS S tile (scale by 8 here)
    #pragma unroll
    for (int i = 0; i < 2; ++i)
      #pragma unroll
      for (int j = 0; j < 2; ++j)
        #pragma unroll
        for (int reg = 0; reg < 4; ++reg)
          Sls[wr * 32 + i * 16 + kblk * 4 + reg][wc * 32 + j * 16 + lrow] =
              8.f * acc[i][j][reg];
    __syncthreads();
    // epilogue: u from registers
    float uw[UEe];
    #pragma unroll
    for (int c = 0; c < UEe; ++c) uw[c] = u_w[h * UEe + c];
    const float ubh = u_b[h];
    float* Sp = S + ((size_t)(b * Hh + h)) * Nn * Nn;
    #pragma unroll
    for (int p = 0; p < 4; ++p) {
      float4 v = *(const float4*)&Sls[p * 16 + trow][tcol];
      v.x += ubh; v.y += ubh; v.z += ubh; v.w += ubh;
      #pragma unroll
      for (int c = 0; c < UEe; ++c) {
        v.x = fmaf(uw[c], ureg[c][p].x, v.x);
        v.y = fmaf(uw[c], ureg[c][p].y, v.y);
        v.z = fmaf(uw[c], ureg[c][p].z, v.z);
        v.w = fmaf(uw[c], ureg[c][p].w, v.w);
      }
      *(float4*)(Sp + (size_t)(i0 + p * 16 + trow) * Nn + j0 + tcol) = v;
    }
  }
}

// -------- fused softmax + P write + P@V -> ctx (split bf16 out) --------

__global__ __launch_bounds__(256) void smctx_kernel(
    float* __restrict__ P, const short* __restrict__ vT,
    short* __restrict__ ctxh, short* __restrict__ ctxl) {
  __shared__ short Ps[32][520];
  __shared__ short Bs[64][136];
  const int z = blockIdx.y, b = z >> 3, hh = z & 7;
  const int row0 = blockIdx.x * 32;
  const int tid = threadIdx.x;
  const int lr = tid >> 3, sub = tid & 7;
  float* Sp = P + (size_t)z * Nn * Nn + (size_t)(row0 + lr) * Nn + sub * 64;
  float4 s[16];
  #pragma unroll
  for (int q = 0; q < 16; ++q) s[q] = *(const float4*)(Sp + q * 4);
  float m = -1e30f;
  #pragma unroll
  for (int q = 0; q < 16; ++q)
    m = fmaxf(m, fmaxf(fmaxf(s[q].x, s[q].y), fmaxf(s[q].z, s[q].w)));
  m = fmaxf(m, __shfl_xor(m, 1));
  m = fmaxf(m, __shfl_xor(m, 2));
  m = fmaxf(m, __shfl_xor(m, 4));
  float sum = 0.f;
  #pragma unroll
  for (int q = 0; q < 16; ++q) {
    s[q].x = __expf(s[q].x - m); s[q].y = __expf(s[q].y - m);
    s[q].z = __expf(s[q].z - m); s[q].w = __expf(s[q].w - m);
    sum += (s[q].x + s[q].y) + (s[q].z + s[q].w);
  }
  sum += __shfl_xor(sum, 1);
  sum += __shfl_xor(sum, 2);
  sum += __shfl_xor(sum, 4);
  const float rr = 1.f / sum;
  #pragma unroll
  for (int q = 0; q < 16; ++q) {
    s[q].x *= rr; s[q].y *= rr; s[q].z *= rr; s[q].w *= rr;
    *(float4*)(Sp + q * 4) = s[q];
  }
  #pragma unroll
  for (int q = 0; q < 8; ++q) {
    float4 a = s[2 * q], c = s[2 * q + 1];
    short8v pk;
    pk[0] = f2bf(a.x); pk[1] = f2bf(a.y); pk[2] = f2bf(a.z); pk[3] = f2bf(a.w);
    pk[4] = f2bf(c.x); pk[5] = f2bf(c.y); pk[6] = f2bf(c.z); pk[7] = f2bf(c.w);
    *(short8v*)&Ps[lr][sub * 64 + q * 8] = pk;
  }
  const int wave = tid >> 6, lane = tid & 63;
  const int wr = wave >> 1, wc = wave & 1;
  const int lrow = lane & 15, kblk = lane >> 4;
  f32x4 acc0 = {}, acc1 = {};
  for (int kc = 0; kc < 4; ++kc) {
    __syncthreads();
    #pragma unroll
    for (int it = 0; it < 4; ++it) {
      int id = tid + it * 256;
      int rrow = id >> 4, k8 = id & 15;
      *(short8v*)&Bs[rrow][k8 * 8] =
          *(const short8v*)(vT + ((size_t)z * HDd + rrow) * Nn + kc * 128 + k8 * 8);
    }
    __syncthreads();
    #pragma unroll
    for (int ks = 0; ks < 4; ++ks) {
      short8v af = *(const short8v*)&Ps[wr * 16 + lrow][kc * 128 + ks * 32 + kblk * 8];
      short8v b0 = *(const short8v*)&Bs[wc * 32 + lrow][ks * 32 + kblk * 8];
      short8v b1 = *(const short8v*)&Bs[wc * 32 + 16 + lrow][ks * 32 + kblk * 8];
      acc0 = __builtin_amdgcn_mfma_f32_16x16x32_bf16(af, b0, acc0, 0, 0, 0);
      acc1 = __builtin_amdgcn_mfma_f32_16x16x32_bf16(af, b1, acc1, 0, 0, 0);
    }
  }
  const size_t outbase =
      ((size_t)(b * Nn + row0 + wr * 16 + kblk * 4)) * Dd + hh * HDd + wc * 32 + lrow;
  #pragma unroll
  for (int reg = 0; reg < 4; ++reg) {
    short h0, l0, h1, l1;
    split2(acc0[reg], h0, l0);
    split2(acc1[reg], h1, l1);
    ctxh[outbase + (size_t)reg * Dd] = h0;
    ctxl[outbase + (size_t)reg * Dd] = l0;
    ctxh[outbase + (size_t)reg * Dd + 16] = h1;
    ctxl[outbase + (size_t)reg * Dd + 16] = l1;
  }
}

// ---------------- bf16 MFMA NT GEMM (FFN) ----------------

template <int BM, int BN, int EPI>
__global__ __launch_bounds__(256) void mfma_nt_kernel(
    const short* __restrict__ Ag, const short* __restrict__ Wg,
    void* __restrict__ Cv, const float* __restrict__ bias,
    const float* __restrict__ res, int Nc, int K) {
  constexpr int MREP = BM / 32, NREP = BN / 32;
  __shared__ short As[BM][72];
  __shared__ short Bs[BN][72];
  const int tid = threadIdx.x;
  const int wave = tid >> 6, lane = tid & 63;
  const int wr = wave >> 1, wc = wave & 1;
  const int lrow = lane & 15, kblk = lane >> 4;
  const size_t bm = (size_t)blockIdx.y * BM, bn = (size_t)blockIdx.x * BN;
  f32x4 acc[MREP][NREP] = {};
  for (int k0 = 0; k0 < K; k0 += 32) {
    __syncthreads();
    #pragma unroll
    for (int it = 0; it < BM / 64; ++it) {
      int id = tid + it * 256;
      int r = id >> 2, kq = id & 3;
      *(short8v*)&As[r][kq * 8] = *(const short8v*)(Ag + (bm + r) * K + k0 + kq * 8);
    }
    #pragma unroll
    for (int it = 0; it < BN / 64; ++it) {
      int id = tid + it * 256;
      int r = id >> 2, kq = id & 3;
      *(short8v*)&Bs[r][kq * 8] = *(const short8v*)(Wg + (bn + r) * K + k0 + kq * 8);
    }
    __syncthreads();
    short8v af[MREP], bf[NREP];
    #pragma unroll
    for (int i = 0; i < MREP; ++i)
      af[i] = *(const short8v*)&As[wr * (BM / 2) + i * 16 + lrow][kblk * 8];
    #pragma unroll
    for (int j = 0; j < NREP; ++j)
      bf[j] = *(const short8v*)&Bs[wc * (BN / 2) + j * 16 + lrow][kblk * 8];
    #pragma unroll
    for (int i = 0; i < MREP; ++i)
      #pragma unroll
      for (int j = 0; j < NREP; ++j)
        acc[i][j] = __builtin_amdgcn_mfma_f32_16x16x32_bf16(af[i], bf[j], acc[i][j], 0, 0, 0);
  }
  #pragma unroll
  for (int i = 0; i < MREP; ++i) {
    #pragma unroll
    for (int j = 0; j < NREP; ++j) {
      const size_t gcol = bn + wc * (BN / 2) + j * 16 + lrow;
      const float bb = bias[gcol];
      #pragma unroll
      for (int reg = 0; reg < 4; ++reg) {
        const size_t grow = bm + wr * (BM / 2) + i * 16 + kblk * 4 + reg;
        float vv = acc[i][j][reg] + bb;
        if constexpr (EPI == 0) {
          vv = vv / (1.f + __expf(-vv));
          ((short*)Cv)[grow * Nc + gcol] = f2bf(vv);
        } else {
          ((float*)Cv)[grow * Nc + gcol] = vv + res[grow * Nc + gcol];
        }
      }
    }
  }
}

// ---------------- host launch ----------------

extern "C" void kernel_launch(void* const* d_in, const int* in_sizes, int n_in,
                              void* d_out, int out_size, void* d_ws, size_t ws_size,
                              hipStream_t stream) {
  const float* x     = (const float*)d_in[0];
  const float* u     = (const float*)d_in[1];
  const float* ln1_w = (const float*)d_in[2];
  const float* ln1_b = (const float*)d_in[3];
  const float* ln2_w = (const float*)d_in[4];
  const float* ln2_b = (const float*)d_in[5];
  const float* wq    = (const float*)d_in[6];
  const float* wk    = (const float*)d_in[7];
  const float* wv    = (const float*)d_in[8];
  const float* wo    = (const float*)d_in[9];
  const float* bo    = (const float*)d_in[10];
  const float* u_w   = (const float*)d_in[11];
  const float* u_b   = (const float*)d_in[12];
  const float* rms_w = (const float*)d_in[13];
  const float* w1    = (const float*)d_in[14];
  const float* b1    = (const float*)d_in[15];
  const float* w2    = (const float*)d_in[16];
  const float* b2    = (const float*)d_in[17];

  float* out   = (float*)d_out;
  float* attnW = out + (size_t)Bb * Nn * Dd;  // second output: [B,H,N,N]

  const size_t SB = (size_t)Bb * Nn * Dd * 2;  // 8 MB
  char* wsb = (char*)d_ws;
  // slot map (8 MB each):
  // 0: xnh -> vTh -> zbf     | 1: xnl -> ctxh -> h1bf[0:8]
  // 2: qh  -> aout[0:8]      | 3: ql -> aout[8:16]   (h1bf[8:24] after hz)
  // 4: kh  -> h1bf[24:32]    | 5: kl -> hbuf[0:8]
  // 6: vh  -> ctxl -> hbuf[8:16]
  short* xnh  = (short*)(wsb + 0 * SB);
  short* xnl  = (short*)(wsb + 1 * SB);
  short* qh   = (short*)(wsb + 2 * SB);
  short* ql   = (short*)(wsb + 3 * SB);
  short* kh   = (short*)(wsb + 4 * SB);
  short* kl   = (short*)(wsb + 5 * SB);
  short* vh   = (short*)(wsb + 6 * SB);
  short* vTh  = (short*)(wsb + 0 * SB);
  short* ctxh = (short*)(wsb + 1 * SB);
  short* ctxl = (short*)(wsb + 6 * SB);
  float* aout = (float*)(wsb + 2 * SB);
  float* hbuf = (float*)(wsb + 5 * SB);
  short* zbf  = (short*)(wsb + 0 * SB);
  short* h1bf = (short*)(wsb + 1 * SB);  // 32 MB: slots 1-4
  const size_t WTBYTES = 8 * (size_t)Dd * Dd * 2 + 2 * (size_t)DFFf * Dd * 2;
  const size_t wt = (ws_size - WTBYTES) & ~(size_t)255;
  short* wAh = (short*)(wsb + wt);
  short* wAl = wAh + 3 * (size_t)Dd * Dd;
  short* woh = wAl + 3 * (size_t)Dd * Dd;
  short* wol = woh + (size_t)Dd * Dd;
  short* w1h = wol + (size_t)Dd * Dd;
  short* w2h = w1h + (size_t)DFFf * Dd;

  const int MR = Bb * Nn;  // 8192 rows

  // 0. weight converts
  cvt2_kernel<<<256, 256, 0, stream>>>(wq, wAh, wAl, Dd * Dd / 4);
  cvt2_kernel<<<256, 256, 0, stream>>>(wk, wAh + (size_t)Dd * Dd, wAl + (size_t)Dd * Dd, Dd * Dd / 4);
  cvt2_kernel<<<256, 256, 0, stream>>>(wv, wAh + 2 * (size_t)Dd * Dd, wAl + 2 * (size_t)Dd * Dd, Dd * Dd / 4);
  cvt2_kernel<<<256, 256, 0, stream>>>(wo, woh, wol, Dd * Dd / 4);
  cvt_kernel<<<1024, 256, 0, stream>>>(w1, w1h, DFFf * Dd / 4);
  cvt_kernel<<<1024, 256, 0, stream>>>(w2, w2h, DFFf * Dd / 4);

  // 1. LayerNorm1 -> split bf16
  ln1_kernel<<<MR, 256, 0, stream>>>(x, ln1_w, ln1_b, xnh, xnl);

  // 2. merged Q,K,V projection (3-term split MFMA)
  dim3 gQKV(3 * Dd / 64, MR / 128);
  mfma_qkv3_kernel<<<gQKV,256,0,stream>>>(xnh, xnl, wAh, wAl, qh, ql, kh, kl, vh);

  // 3. V transpose per head
  dim3 gVt(Nn / 64, Bb * Hh);
  vt_kernel<<<gVt, 256, 0, stream>>>(vh, vTh);

  // 4. scores: all heads per block, u read once
  dim3 gSc(Nn / 64, Nn / 64, Bb);
  scores8_kernel<<<gSc, 256, 0, stream>>>(qh, ql, kh, kl, attnW, u, u_w, u_b);

  // 5. fused softmax (in-place P) + P@V -> ctx split bf16
  dim3 gSm(Nn / 32, Bb * Hh);
  smctx_kernel<<<gSm, 256, 0, stream>>>(attnW, vTh, ctxh, ctxl);

  // 6. attn_out = ctx @ wo^T + bo (3-term, f32 out)
  dim3 gProj(Dd / 64, MR / 128);
  mfma_nt3_kernel<1><<<gProj,256,0,stream>>>(ctxh, ctxl, woh, wol, aout, nullptr, bo, Dd, Dd);

  // 7. h = LN2(attn_out) + x ; zbf = bf16(RMSNorm(h))
  hz_kernel<<<MR, 256, 0, stream>>>(aout, x, ln2_w, ln2_b, rms_w, hbuf, zbf);

  // 8/9. FFN bf16 MFMA, single pass (h1bf = 32 MB, slots 1-4)
  dim3 gF1(DFFf / 128, MR / 128);
  mfma_nt_kernel<128,128,0><<<gF1,256,0,stream>>>(
      zbf, w1h, h1bf, b1, nullptr, DFFf, Dd);
  dim3 gF2(Dd / 128, MR / 64);
  mfma_nt_kernel<64,128,1><<<gF2,256,0,stream>>>(
      h1bf, w2h, out, b2, hbuf, Dd, DFFf);
}

// Round 10
// 346.227 us; speedup vs baseline: 2.9691x; 1.0075x over previous
//
#include <hip/hip_runtime.h>
#include <math.h>

static constexpr int Bb  = 16;
static constexpr int Nn  = 512;
static constexpr int Dd  = 512;
static constexpr int Hh  = 8;
static constexpr int HDd = 64;
static constexpr int UEe = 6;
static constexpr int DFFf= 2048;

typedef __attribute__((ext_vector_type(8))) short short8v;
typedef __attribute__((ext_vector_type(4))) float f32x4;

__device__ __forceinline__ short f2bf(float f) {
  unsigned u = __float_as_uint(f);
  unsigned r = (u + 0x7fffu + ((u >> 16) & 1u)) >> 16;
  return (short)r;
}
__device__ __forceinline__ float bf2f(short h) {
  return __uint_as_float(((unsigned)(unsigned short)h) << 16);
}
__device__ __forceinline__ void split2(float v, short& hi, short& lo) {
  hi = f2bf(v);
  lo = f2bf(v - bf2f(hi));
}

// ---------------- block reduction helpers (256 threads, 4 waves) ----------------

__device__ __forceinline__ float2 block_sum2(float a, float b, float* sb) {
  #pragma unroll
  for (int o = 32; o; o >>= 1) { a += __shfl_down(a, o); b += __shfl_down(b, o); }
  const int lane = threadIdx.x & 63, wid = threadIdx.x >> 6;
  if (lane == 0) { sb[wid] = a; sb[4 + wid] = b; }
  __syncthreads();
  float ra = sb[0] + sb[1] + sb[2] + sb[3];
  float rb = sb[4] + sb[5] + sb[6] + sb[7];
  __syncthreads();
  return make_float2(ra, rb);
}

__device__ __forceinline__ float block_sum1(float a, float* sb) {
  #pragma unroll
  for (int o = 32; o; o >>= 1) a += __shfl_down(a, o);
  const int lane = threadIdx.x & 63, wid = threadIdx.x >> 6;
  if (lane == 0) sb[wid] = a;
  __syncthreads();
  float ra = sb[0] + sb[1] + sb[2] + sb[3];
  __syncthreads();
  return ra;
}

// ---------------- LayerNorm on x -> xn (split bf16 hi/lo) ----------------

__global__ __launch_bounds__(256) void ln1_kernel(
    const float* __restrict__ x, const float* __restrict__ w,
    const float* __restrict__ b, short* __restrict__ oh, short* __restrict__ ol) {
  __shared__ float sb[8];
  const size_t row = blockIdx.x;
  const int t = threadIdx.x;
  const float* xr = x + row * Dd;
  float2 xv = *(const float2*)(xr + 2 * t);
  float2 r = block_sum2(xv.x + xv.y, xv.x * xv.x + xv.y * xv.y, sb);
  const float mu = r.x * (1.f / Dd);
  const float var = r.y * (1.f / Dd) - mu * mu;
  const float rstd = rsqrtf(var + 1e-5f);
  float2 wv = *(const float2*)(w + 2 * t);
  float2 bv = *(const float2*)(b + 2 * t);
  float v0 = (xv.x - mu) * rstd * wv.x + bv.x;
  float v1 = (xv.y - mu) * rstd * wv.y + bv.y;
  short2 h2, l2;
  split2(v0, h2.x, l2.x);
  split2(v1, h2.y, l2.y);
  *(short2*)(oh + row * Dd + 2 * t) = h2;
  *(short2*)(ol + row * Dd + 2 * t) = l2;
}

// ------- LN2(attn_out)+residual -> h (f32) ; RMSNorm(h) -> zbf (bf16) -------

__global__ __launch_bounds__(256) void hz_kernel(
    const float* __restrict__ ao, const float* __restrict__ xres,
    const float* __restrict__ w, const float* __restrict__ b,
    const float* __restrict__ rw,
    float* __restrict__ h, short* __restrict__ zbf) {
  __shared__ float sb[8];
  const size_t row = blockIdx.x;
  const int t = threadIdx.x;
  float2 av = *(const float2*)(ao + row * Dd + 2 * t);
  float2 r = block_sum2(av.x + av.y, av.x * av.x + av.y * av.y, sb);
  const float mu = r.x * (1.f / Dd);
  const float var = r.y * (1.f / Dd) - mu * mu;
  const float rstd = rsqrtf(var + 1e-5f);
  float2 wv = *(const float2*)(w + 2 * t);
  float2 bv = *(const float2*)(b + 2 * t);
  float2 xv = *(const float2*)(xres + row * Dd + 2 * t);
  float2 hv;
  hv.x = (av.x - mu) * rstd * wv.x + bv.x + xv.x;
  hv.y = (av.y - mu) * rstd * wv.y + bv.y + xv.y;
  *(float2*)(h + row * Dd + 2 * t) = hv;
  float ms = block_sum1(hv.x * hv.x + hv.y * hv.y, sb) * (1.f / Dd);
  const float rr = rsqrtf(ms + 1.1920929e-07f);
  float2 rwv = *(const float2*)(rw + 2 * t);
  short2 zv;
  zv.x = f2bf(hv.x * rr * rwv.x);
  zv.y = f2bf(hv.y * rr * rwv.y);
  *(short2*)(zbf + row * Dd + 2 * t) = zv;
}

// ---------------- f32 -> bf16 converts ----------------

__global__ __launch_bounds__(256) void cvt_kernel(
    const float* __restrict__ in, short* __restrict__ out, int n4) {
  int i = blockIdx.x * 256 + threadIdx.x;
  if (i < n4) {
    float4 v = ((const float4*)in)[i];
    short4 o;
    o.x = f2bf(v.x); o.y = f2bf(v.y); o.z = f2bf(v.z); o.w = f2bf(v.w);
    ((short4*)out)[i] = o;
  }
}

__global__ __launch_bounds__(256) void cvt2_kernel(
    const float* __restrict__ in, short* __restrict__ hi,
    short* __restrict__ lo, int n4) {
  int i = blockIdx.x * 256 + threadIdx.x;
  if (i < n4) {
    float4 v = ((const float4*)in)[i];
    short4 h, l;
    split2(v.x, h.x, l.x); split2(v.y, h.y, l.y);
    split2(v.z, h.z, l.z); split2(v.w, h.w, l.w);
    ((short4*)hi)[i] = h;
    ((short4*)lo)[i] = l;
  }
}

// -------- V transpose: v[8192][512] bf16 -> vT[b][h][hd(64)][n(512)] bf16 --------

__global__ __launch_bounds__(256) void vt_kernel(
    const short* __restrict__ v, short* __restrict__ vT) {
  __shared__ short Lt[64][72];
  const int z = blockIdx.y, b = z >> 3, hh = z & 7;
  const int n0 = blockIdx.x * 64;
  const int tid = threadIdx.x;
  #pragma unroll
  for (int it = 0; it < 2; ++it) {
    int id = tid + it * 256;
    int r = id >> 3, c8 = id & 7;
    *(short8v*)&Lt[r][c8 * 8] =
        *(const short8v*)(v + ((size_t)(b * Nn + n0 + r)) * Dd + hh * HDd + c8 * 8);
  }
  __syncthreads();
  #pragma unroll
  for (int it = 0; it < 2; ++it) {
    int id = tid + it * 256;
    int c = id >> 3, r8 = id & 7;
    short8v g;
    #pragma unroll
    for (int k = 0; k < 8; ++k) g[k] = Lt[r8 * 8 + k][c];
    *(short8v*)(vT + ((size_t)z * HDd + c) * Nn + n0 + r8 * 8) = g;
  }
}

// ------ merged QKV 3-term split-bf16 NT GEMM ------

__global__ __launch_bounds__(256) void mfma_qkv3_kernel(
    const short* __restrict__ Ah, const short* __restrict__ Al,
    const short* __restrict__ Wh, const short* __restrict__ Wl,
    short* __restrict__ qh_, short* __restrict__ ql_,
    short* __restrict__ kh_, short* __restrict__ kl_,
    short* __restrict__ vh_) {
  constexpr int MREP = 4, NREP = 2;
  __shared__ short Ash[128][40], Asl[128][40], Bsh[64][40], Bsl[64][40];
  const int tid = threadIdx.x;
  const int wave = tid >> 6, lane = tid & 63;
  const int wr = wave >> 1, wc = wave & 1;
  const int lrow = lane & 15, kblk = lane >> 4;
  const size_t bm = (size_t)blockIdx.y * 128, bn = (size_t)blockIdx.x * 64;
  f32x4 acc[MREP][NREP] = {};
  for (int k0 = 0; k0 < Dd; k0 += 32) {
    __syncthreads();
    #pragma unroll
    for (int it = 0; it < 2; ++it) {
      int id = tid + it * 256;
      int r = id >> 2, kq = id & 3;
      const size_t go = (bm + r) * Dd + k0 + kq * 8;
      *(short8v*)&Ash[r][kq * 8] = *(const short8v*)(Ah + go);
      *(short8v*)&Asl[r][kq * 8] = *(const short8v*)(Al + go);
    }
    {
      int r = tid >> 2, kq = tid & 3;
      const size_t go = (bn + r) * Dd + k0 + kq * 8;
      *(short8v*)&Bsh[r][kq * 8] = *(const short8v*)(Wh + go);
      *(short8v*)&Bsl[r][kq * 8] = *(const short8v*)(Wl + go);
    }
    __syncthreads();
    short8v afh[MREP], afl[MREP], bfh[NREP], bfl[NREP];
    #pragma unroll
    for (int i = 0; i < MREP; ++i) {
      afh[i] = *(const short8v*)&Ash[wr * 64 + i * 16 + lrow][kblk * 8];
      afl[i] = *(const short8v*)&Asl[wr * 64 + i * 16 + lrow][kblk * 8];
    }
    #pragma unroll
    for (int j = 0; j < NREP; ++j) {
      bfh[j] = *(const short8v*)&Bsh[wc * 32 + j * 16 + lrow][kblk * 8];
      bfl[j] = *(const short8v*)&Bsl[wc * 32 + j * 16 + lrow][kblk * 8];
    }
    #pragma unroll
    for (int i = 0; i < MREP; ++i)
      #pragma unroll
      for (int j = 0; j < NREP; ++j) {
        acc[i][j] = __builtin_amdgcn_mfma_f32_16x16x32_bf16(afh[i], bfh[j], acc[i][j], 0, 0, 0);
        acc[i][j] = __builtin_amdgcn_mfma_f32_16x16x32_bf16(afl[i], bfh[j], acc[i][j], 0, 0, 0);
        acc[i][j] = __builtin_amdgcn_mfma_f32_16x16x32_bf16(afh[i], bfl[j], acc[i][j], 0, 0, 0);
      }
  }
  const int seg = (int)(bn >> 9);  // uniform per block
  short* dsth = seg == 0 ? qh_ : (seg == 1 ? kh_ : vh_);
  short* dstl = seg == 0 ? ql_ : kl_;
  #pragma unroll
  for (int i = 0; i < MREP; ++i) {
    #pragma unroll
    for (int j = 0; j < NREP; ++j) {
      const size_t gcol = (bn & 511) + wc * 32 + j * 16 + lrow;
      #pragma unroll
      for (int reg = 0; reg < 4; ++reg) {
        const size_t grow = bm + wr * 64 + i * 16 + kblk * 4 + reg;
        float vv = acc[i][j][reg];
        if (seg < 2) {
          short hh_, ll_;
          split2(vv, hh_, ll_);
          dsth[grow * Dd + gcol] = hh_;
          dstl[grow * Dd + gcol] = ll_;
        } else {
          dsth[grow * Dd + gcol] = f2bf(vv);
        }
      }
    }
  }
}

// ------ 3-term split-bf16 NT GEMM (out-proj): C = (Ah+Al)@(Wh+Wl)^T ------

template <int EPI>
__global__ __launch_bounds__(256) void mfma_nt3_kernel(
    const short* __restrict__ Ah, const short* __restrict__ Al,
    const short* __restrict__ Wh, const short* __restrict__ Wl,
    void* __restrict__ C1, void* __restrict__ C2,
    const float* __restrict__ bias, int Nc, int K) {
  constexpr int BM = 128, BN = 64;
  constexpr int MREP = 4, NREP = 2;
  __shared__ short Ash[BM][40], Asl[BM][40], Bsh[BN][40], Bsl[BN][40];
  const int tid = threadIdx.x;
  const int wave = tid >> 6, lane = tid & 63;
  const int wr = wave >> 1, wc = wave & 1;
  const int lrow = lane & 15, kblk = lane >> 4;
  const size_t bm = (size_t)blockIdx.y * BM, bn = (size_t)blockIdx.x * BN;
  f32x4 acc[MREP][NREP] = {};
  for (int k0 = 0; k0 < K; k0 += 32) {
    __syncthreads();
    #pragma unroll
    for (int it = 0; it < 2; ++it) {
      int id = tid + it * 256;
      int r = id >> 2, kq = id & 3;
      const size_t go = (bm + r) * K + k0 + kq * 8;
      *(short8v*)&Ash[r][kq * 8] = *(const short8v*)(Ah + go);
      *(short8v*)&Asl[r][kq * 8] = *(const short8v*)(Al + go);
    }
    {
      int r = tid >> 2, kq = tid & 3;
      const size_t go = (bn + r) * K + k0 + kq * 8;
      *(short8v*)&Bsh[r][kq * 8] = *(const short8v*)(Wh + go);
      *(short8v*)&Bsl[r][kq * 8] = *(const short8v*)(Wl + go);
    }
    __syncthreads();
    short8v afh[MREP], afl[MREP], bfh[NREP], bfl[NREP];
    #pragma unroll
    for (int i = 0; i < MREP; ++i) {
      afh[i] = *(const short8v*)&Ash[wr * 64 + i * 16 + lrow][kblk * 8];
      afl[i] = *(const short8v*)&Asl[wr * 64 + i * 16 + lrow][kblk * 8];
    }
    #pragma unroll
    for (int j = 0; j < NREP; ++j) {
      bfh[j] = *(const short8v*)&Bsh[wc * 32 + j * 16 + lrow][kblk * 8];
      bfl[j] = *(const short8v*)&Bsl[wc * 32 + j * 16 + lrow][kblk * 8];
    }
    #pragma unroll
    for (int i = 0; i < MREP; ++i)
      #pragma unroll
      for (int j = 0; j < NREP; ++j) {
        acc[i][j] = __builtin_amdgcn_mfma_f32_16x16x32_bf16(afh[i], bfh[j], acc[i][j], 0, 0, 0);
        acc[i][j] = __builtin_amdgcn_mfma_f32_16x16x32_bf16(afl[i], bfh[j], acc[i][j], 0, 0, 0);
        acc[i][j] = __builtin_amdgcn_mfma_f32_16x16x32_bf16(afh[i], bfl[j], acc[i][j], 0, 0, 0);
      }
  }
  #pragma unroll
  for (int i = 0; i < MREP; ++i) {
    #pragma unroll
    for (int j = 0; j < NREP; ++j) {
      const size_t gcol = bn + wc * 32 + j * 16 + lrow;
      float bb = 0.f;
      if constexpr (EPI == 1) bb = bias[gcol];
      #pragma unroll
      for (int reg = 0; reg < 4; ++reg) {
        const size_t grow = bm + wr * 64 + i * 16 + kblk * 4 + reg;
        float vv = acc[i][j][reg] + bb;
        if constexpr (EPI == 0) {
          short hh_, ll_;
          split2(vv, hh_, ll_);
          ((short*)C1)[grow * Nc + gcol] = hh_;
          ((short*)C2)[grow * Nc + gcol] = ll_;
        } else if constexpr (EPI == 1) {
          ((float*)C1)[grow * Nc + gcol] = vv;
        } else {
          ((short*)C1)[grow * Nc + gcol] = f2bf(vv);
        }
      }
    }
  }
}

// -------- scores8: all heads per block, LDS union, u via L2-hot re-reads --------
// grid (8 j-tiles, 8 i-tiles, 16 b). 256 threads, 2x2 waves, 64x64 tile/head.
// Staging (4 x [64][72] shorts = 36864 B) unions with Sls ([64][68] f32 = 17408 B):
// phases alternate per head with 4 barriers. LDS 36.9 KB -> 4 blocks/CU.
// u tile (98 KB/block) is re-read per head: head 0 pays HBM, heads 1-7 hit L2/L3.

__global__ __launch_bounds__(256) void scores8_kernel(
    const short* __restrict__ qh, const short* __restrict__ ql,
    const short* __restrict__ kh, const short* __restrict__ kl,
    float* __restrict__ S, const float* __restrict__ u,
    const float* __restrict__ u_w, const float* __restrict__ u_b) {
  __shared__ __align__(16) char smem[36864];
  short (*Qsh)[72] = (short(*)[72])(smem + 0);
  short (*Qsl)[72] = (short(*)[72])(smem + 9216);
  short (*Ksh)[72] = (short(*)[72])(smem + 18432);
  short (*Ksl)[72] = (short(*)[72])(smem + 27648);
  float (*Sls)[68] = (float(*)[68])(smem);  // overlays Q staging (phase-disjoint)
  const int b = blockIdx.z;
  const int i0 = blockIdx.y * 64, j0 = blockIdx.x * 64;
  const int tid = threadIdx.x;
  const int wave = tid >> 6, lane = tid & 63;
  const int wr = wave >> 1, wc = wave & 1;
  const int lrow = lane & 15, kblk = lane >> 4;
  const int trow = tid >> 4;          // 0..15
  const int tcol = (tid & 15) * 4;    // 0,4,..,60
  const float* ub_ = u + (size_t)b * UEe * Nn * Nn;

  for (int h = 0; h < Hh; ++h) {
    __syncthreads();  // prev head: epilogue Sls reads done before staging writes
    #pragma unroll
    for (int it = 0; it < 2; ++it) {
      int id = tid + it * 256;
      int r = id >> 3, kq = id & 7;
      const size_t gq = ((size_t)(b * Nn) + i0 + r) * Dd + h * HDd + kq * 8;
      const size_t gk = ((size_t)(b * Nn) + j0 + r) * Dd + h * HDd + kq * 8;
      *(short8v*)&Qsh[r][kq * 8] = *(const short8v*)(qh + gq);
      *(short8v*)&Qsl[r][kq * 8] = *(const short8v*)(ql + gq);
      *(short8v*)&Ksh[r][kq * 8] = *(const short8v*)(kh + gk);
      *(short8v*)&Ksl[r][kq * 8] = *(const short8v*)(kl + gk);
    }
    __syncthreads();
    f32x4 acc[2][2] = {};
    #pragma unroll
    for (int ks = 0; ks < 2; ++ks) {
      short8v afh[2], afl[2], bfh[2], bfl[2];
      #pragma unroll
      for (int i = 0; i < 2; ++i) {
        afh[i] = *(const short8v*)&Qsh[wr * 32 + i * 16 + lrow][ks * 32 + kblk * 8];
        afl[i] = *(const short8v*)&Qsl[wr * 32 + i * 16 + lrow][ks * 32 + kblk * 8];
      }
      #pragma unroll
      for (int j = 0; j < 2; ++j) {
        bfh[j] = *(const short8v*)&Ksh[wc * 32 + j * 16 + lrow][ks * 32 + kblk * 8];
        bfl[j] = *(const short8v*)&Ksl[wc * 32 + j * 16 + lrow][ks * 32 + kblk * 8];
      }
      #pragma unroll
      for (int i = 0; i < 2; ++i)
        #pragma unroll
        for (int j = 0; j < 2; ++j) {
          acc[i][j] = __builtin_amdgcn_mfma_f32_16x16x32_bf16(afh[i], bfh[j], acc[i][j], 0, 0, 0);
          acc[i][j] = __builtin_amdgcn_mfma_f32_16x16x32_bf16(afl[i], bfh[j], acc[i][j], 0, 0, 0);
          acc[i][j] = __builtin_amdgcn_mfma_f32_16x16x32_bf16(afh[i], bfl[j], acc[i][j], 0, 0, 0);
        }
    }
    __syncthreads();  // staging reads done before Sls overwrites the same LDS
    #pragma unroll
    for (int i = 0; i < 2; ++i)
      #pragma unroll
      for (int j = 0; j < 2; ++j)
        #pragma unroll
        for (int reg = 0; reg < 4; ++reg)
          Sls[wr * 32 + i * 16 + kblk * 4 + reg][wc * 32 + j * 16 + lrow] =
              8.f * acc[i][j][reg];
    __syncthreads();
    // epilogue: coalesced float4 u loads (L2-hot after first head) + store
    float uw[UEe];
    #pragma unroll
    for (int c = 0; c < UEe; ++c) uw[c] = u_w[h * UEe + c];
    const float ubh = u_b[h];
    float* Sp = S + ((size_t)(b * Hh + h)) * Nn * Nn;
    #pragma unroll
    for (int p = 0; p < 4; ++p) {
      const size_t goff = (size_t)(i0 + p * 16 + trow) * Nn + j0 + tcol;
      float4 v = *(const float4*)&Sls[p * 16 + trow][tcol];
      v.x += ubh; v.y += ubh; v.z += ubh; v.w += ubh;
      #pragma unroll
      for (int c = 0; c < UEe; ++c) {
        float4 uv = *(const float4*)(ub_ + (size_t)c * Nn * Nn + goff);
        v.x = fmaf(uw[c], uv.x, v.x);
        v.y = fmaf(uw[c], uv.y, v.y);
        v.z = fmaf(uw[c], uv.z, v.z);
        v.w = fmaf(uw[c], uv.w, v.w);
      }
      *(float4*)(Sp + goff) = v;
    }
  }
}

// -------- fused softmax + P write + P@V -> ctx (split bf16 out) --------

__global__ __launch_bounds__(256) void smctx_kernel(
    float* __restrict__ P, const short* __restrict__ vT,
    short* __restrict__ ctxh, short* __restrict__ ctxl) {
  __shared__ short Ps[32][520];
  __shared__ short Bs[64][136];
  const int z = blockIdx.y, b = z >> 3, hh = z & 7;
  const int row0 = blockIdx.x * 32;
  const int tid = threadIdx.x;
  const int lr = tid >> 3, sub = tid & 7;
  float* Sp = P + (size_t)z * Nn * Nn + (size_t)(row0 + lr) * Nn + sub * 64;
  float4 s[16];
  #pragma unroll
  for (int q = 0; q < 16; ++q) s[q] = *(const float4*)(Sp + q * 4);
  float m = -1e30f;
  #pragma unroll
  for (int q = 0; q < 16; ++q)
    m = fmaxf(m, fmaxf(fmaxf(s[q].x, s[q].y), fmaxf(s[q].z, s[q].w)));
  m = fmaxf(m, __shfl_xor(m, 1));
  m = fmaxf(m, __shfl_xor(m, 2));
  m = fmaxf(m, __shfl_xor(m, 4));
  float sum = 0.f;
  #pragma unroll
  for (int q = 0; q < 16; ++q) {
    s[q].x = __expf(s[q].x - m); s[q].y = __expf(s[q].y - m);
    s[q].z = __expf(s[q].z - m); s[q].w = __expf(s[q].w - m);
    sum += (s[q].x + s[q].y) + (s[q].z + s[q].w);
  }
  sum += __shfl_xor(sum, 1);
  sum += __shfl_xor(sum, 2);
  sum += __shfl_xor(sum, 4);
  const float rr = 1.f / sum;
  #pragma unroll
  for (int q = 0; q < 16; ++q) {
    s[q].x *= rr; s[q].y *= rr; s[q].z *= rr; s[q].w *= rr;
    *(float4*)(Sp + q * 4) = s[q];
  }
  #pragma unroll
  for (int q = 0; q < 8; ++q) {
    float4 a = s[2 * q], c = s[2 * q + 1];
    short8v pk;
    pk[0] = f2bf(a.x); pk[1] = f2bf(a.y); pk[2] = f2bf(a.z); pk[3] = f2bf(a.w);
    pk[4] = f2bf(c.x); pk[5] = f2bf(c.y); pk[6] = f2bf(c.z); pk[7] = f2bf(c.w);
    *(short8v*)&Ps[lr][sub * 64 + q * 8] = pk;
  }
  const int wave = tid >> 6, lane = tid & 63;
  const int wr = wave >> 1, wc = wave & 1;
  const int lrow = lane & 15, kblk = lane >> 4;
  f32x4 acc0 = {}, acc1 = {};
  for (int kc = 0; kc < 4; ++kc) {
    __syncthreads();
    #pragma unroll
    for (int it = 0; it < 4; ++it) {
      int id = tid + it * 256;
      int rrow = id >> 4, k8 = id & 15;
      *(short8v*)&Bs[rrow][k8 * 8] =
          *(const short8v*)(vT + ((size_t)z * HDd + rrow) * Nn + kc * 128 + k8 * 8);
    }
    __syncthreads();
    #pragma unroll
    for (int ks = 0; ks < 4; ++ks) {
      short8v af = *(const short8v*)&Ps[wr * 16 + lrow][kc * 128 + ks * 32 + kblk * 8];
      short8v b0 = *(const short8v*)&Bs[wc * 32 + lrow][ks * 32 + kblk * 8];
      short8v b1 = *(const short8v*)&Bs[wc * 32 + 16 + lrow][ks * 32 + kblk * 8];
      acc0 = __builtin_amdgcn_mfma_f32_16x16x32_bf16(af, b0, acc0, 0, 0, 0);
      acc1 = __builtin_amdgcn_mfma_f32_16x16x32_bf16(af, b1, acc1, 0, 0, 0);
    }
  }
  const size_t outbase =
      ((size_t)(b * Nn + row0 + wr * 16 + kblk * 4)) * Dd + hh * HDd + wc * 32 + lrow;
  #pragma unroll
  for (int reg = 0; reg < 4; ++reg) {
    short h0, l0, h1, l1;
    split2(acc0[reg], h0, l0);
    split2(acc1[reg], h1, l1);
    ctxh[outbase + (size_t)reg * Dd] = h0;
    ctxl[outbase + (size_t)reg * Dd] = l0;
    ctxh[outbase + (size_t)reg * Dd + 16] = h1;
    ctxl[outbase + (size_t)reg * Dd + 16] = l1;
  }
}

// ---------------- bf16 MFMA NT GEMM (FFN) ----------------

template <int BM, int BN, int EPI>
__global__ __launch_bounds__(256) void mfma_nt_kernel(
    const short* __restrict__ Ag, const short* __restrict__ Wg,
    void* __restrict__ Cv, const float* __restrict__ bias,
    const float* __restrict__ res, int Nc, int K) {
  constexpr int MREP = BM / 32, NREP = BN / 32;
  __shared__ short As[BM][72];
  __shared__ short Bs[BN][72];
  const int tid = threadIdx.x;
  const int wave = tid >> 6, lane = tid & 63;
  const int wr = wave >> 1, wc = wave & 1;
  const int lrow = lane & 15, kblk = lane >> 4;
  const size_t bm = (size_t)blockIdx.y * BM, bn = (size_t)blockIdx.x * BN;
  f32x4 acc[MREP][NREP] = {};
  for (int k0 = 0; k0 < K; k0 += 32) {
    __syncthreads();
    #pragma unroll
    for (int it = 0; it < BM / 64; ++it) {
      int id = tid + it * 256;
      int r = id >> 2, kq = id & 3;
      *(short8v*)&As[r][kq * 8] = *(const short8v*)(Ag + (bm + r) * K + k0 + kq * 8);
    }
    #pragma unroll
    for (int it = 0; it < BN / 64; ++it) {
      int id = tid + it * 256;
      int r = id >> 2, kq = id & 3;
      *(short8v*)&Bs[r][kq * 8] = *(const short8v*)(Wg + (bn + r) * K + k0 + kq * 8);
    }
    __syncthreads();
    short8v af[MREP], bf[NREP];
    #pragma unroll
    for (int i = 0; i < MREP; ++i)
      af[i] = *(const short8v*)&As[wr * (BM / 2) + i * 16 + lrow][kblk * 8];
    #pragma unroll
    for (int j = 0; j < NREP; ++j)
      bf[j] = *(const short8v*)&Bs[wc * (BN / 2) + j * 16 + lrow][kblk * 8];
    #pragma unroll
    for (int i = 0; i < MREP; ++i)
      #pragma unroll
      for (int j = 0; j < NREP; ++j)
        acc[i][j] = __builtin_amdgcn_mfma_f32_16x16x32_bf16(af[i], bf[j], acc[i][j], 0, 0, 0);
  }
  #pragma unroll
  for (int i = 0; i < MREP; ++i) {
    #pragma unroll
    for (int j = 0; j < NREP; ++j) {
      const size_t gcol = bn + wc * (BN / 2) + j * 16 + lrow;
      const float bb = bias[gcol];
      #pragma unroll
      for (int reg = 0; reg < 4; ++reg) {
        const size_t grow = bm + wr * (BM / 2) + i * 16 + kblk * 4 + reg;
        float vv = acc[i][j][reg] + bb;
        if constexpr (EPI == 0) {
          vv = vv / (1.f + __expf(-vv));
          ((short*)Cv)[grow * Nc + gcol] = f2bf(vv);
        } else {
          ((float*)Cv)[grow * Nc + gcol] = vv + res[grow * Nc + gcol];
        }
      }
    }
  }
}

// ---------------- host launch ----------------

extern "C" void kernel_launch(void* const* d_in, const int* in_sizes, int n_in,
                              void* d_out, int out_size, void* d_ws, size_t ws_size,
                              hipStream_t stream) {
  const float* x     = (const float*)d_in[0];
  const float* u     = (const float*)d_in[1];
  const float* ln1_w = (const float*)d_in[2];
  const float* ln1_b = (const float*)d_in[3];
  const float* ln2_w = (const float*)d_in[4];
  const float* ln2_b = (const float*)d_in[5];
  const float* wq    = (const float*)d_in[6];
  const float* wk    = (const float*)d_in[7];
  const float* wv    = (const float*)d_in[8];
  const float* wo    = (const float*)d_in[9];
  const float* bo    = (const float*)d_in[10];
  const float* u_w   = (const float*)d_in[11];
  const float* u_b   = (const float*)d_in[12];
  const float* rms_w = (const float*)d_in[13];
  const float* w1    = (const float*)d_in[14];
  const float* b1    = (const float*)d_in[15];
  const float* w2    = (const float*)d_in[16];
  const float* b2    = (const float*)d_in[17];

  float* out   = (float*)d_out;
  float* attnW = out + (size_t)Bb * Nn * Dd;  // second output: [B,H,N,N]

  const size_t SB = (size_t)Bb * Nn * Dd * 2;  // 8 MB
  char* wsb = (char*)d_ws;
  // slot map (8 MB each):
  // 0: xnh -> vTh -> zbf     | 1: xnl -> ctxh -> h1bf[0:8]
  // 2: qh  -> aout[0:8]      | 3: ql -> aout[8:16]   (h1bf[8:24] after hz)
  // 4: kh  -> h1bf[24:32]    | 5: kl -> hbuf[0:8]
  // 6: vh  -> ctxl -> hbuf[8:16]
  short* xnh  = (short*)(wsb + 0 * SB);
  short* xnl  = (short*)(wsb + 1 * SB);
  short* qh   = (short*)(wsb + 2 * SB);
  short* ql   = (short*)(wsb + 3 * SB);
  short* kh   = (short*)(wsb + 4 * SB);
  short* kl   = (short*)(wsb + 5 * SB);
  short* vh   = (short*)(wsb + 6 * SB);
  short* vTh  = (short*)(wsb + 0 * SB);
  short* ctxh = (short*)(wsb + 1 * SB);
  short* ctxl = (short*)(wsb + 6 * SB);
  float* aout = (float*)(wsb + 2 * SB);
  float* hbuf = (float*)(wsb + 5 * SB);
  short* zbf  = (short*)(wsb + 0 * SB);
  short* h1bf = (short*)(wsb + 1 * SB);  // 32 MB: slots 1-4
  const size_t WTBYTES = 8 * (size_t)Dd * Dd * 2 + 2 * (size_t)DFFf * Dd * 2;
  const size_t wt = (ws_size - WTBYTES) & ~(size_t)255;
  short* wAh = (short*)(wsb + wt);
  short* wAl = wAh + 3 * (size_t)Dd * Dd;
  short* woh = wAl + 3 * (size_t)Dd * Dd;
  short* wol = woh + (size_t)Dd * Dd;
  short* w1h = wol + (size_t)Dd * Dd;
  short* w2h = w1h + (size_t)DFFf * Dd;

  const int MR = Bb * Nn;  // 8192 rows

  // 0. weight converts
  cvt2_kernel<<<256, 256, 0, stream>>>(wq, wAh, wAl, Dd * Dd / 4);
  cvt2_kernel<<<256, 256, 0, stream>>>(wk, wAh + (size_t)Dd * Dd, wAl + (size_t)Dd * Dd, Dd * Dd / 4);
  cvt2_kernel<<<256, 256, 0, stream>>>(wv, wAh + 2 * (size_t)Dd * Dd, wAl + 2 * (size_t)Dd * Dd, Dd * Dd / 4);
  cvt2_kernel<<<256, 256, 0, stream>>>(wo, woh, wol, Dd * Dd / 4);
  cvt_kernel<<<1024, 256, 0, stream>>>(w1, w1h, DFFf * Dd / 4);
  cvt_kernel<<<1024, 256, 0, stream>>>(w2, w2h, DFFf * Dd / 4);

  // 1. LayerNorm1 -> split bf16
  ln1_kernel<<<MR, 256, 0, stream>>>(x, ln1_w, ln1_b, xnh, xnl);

  // 2. merged Q,K,V projection (3-term split MFMA)
  dim3 gQKV(3 * Dd / 64, MR / 128);
  mfma_qkv3_kernel<<<gQKV,256,0,stream>>>(xnh, xnl, wAh, wAl, qh, ql, kh, kl, vh);

  // 3. V transpose per head
  dim3 gVt(Nn / 64, Bb * Hh);
  vt_kernel<<<gVt, 256, 0, stream>>>(vh, vTh);

  // 4. scores: all heads per block, LDS union, u L2-hot
  dim3 gSc(Nn / 64, Nn / 64, Bb);
  scores8_kernel<<<gSc, 256, 0, stream>>>(qh, ql, kh, kl, attnW, u, u_w, u_b);

  // 5. fused softmax (in-place P) + P@V -> ctx split bf16
  dim3 gSm(Nn / 32, Bb * Hh);
  smctx_kernel<<<gSm, 256, 0, stream>>>(attnW, vTh, ctxh, ctxl);

  // 6. attn_out = ctx @ wo^T + bo (3-term, f32 out)
  dim3 gProj(Dd / 64, MR / 128);
  mfma_nt3_kernel<1><<<gProj,256,0,stream>>>(ctxh, ctxl, woh, wol, aout, nullptr, bo, Dd, Dd);

  // 7. h = LN2(attn_out) + x ; zbf = bf16(RMSNorm(h))
  hz_kernel<<<MR, 256, 0, stream>>>(aout, x, ln2_w, ln2_b, rms_w, hbuf, zbf);

  // 8/9. FFN bf16 MFMA, single pass (h1bf = 32 MB, slots 1-4)
  dim3 gF1(DFFf / 128, MR / 128);
  mfma_nt_kernel<128,128,0><<<gF1,256,0,stream>>>(
      zbf, w1h, h1bf, b1, nullptr, DFFf, Dd);
  dim3 gF2(Dd / 128, MR / 64);
  mfma_nt_kernel<64,128,1><<<gF2,256,0,stream>>>(
      h1bf, w2h, out, b2, hbuf, Dd, DFFf);
}